// Round 21
// baseline (747.208 us; speedup 1.0000x reference)
//
#include <hip/hip_runtime.h>
#include <math.h>

#define NB 4
#define SL 1024
#define DM 1024
#define NH 16
#define HD 64

typedef short v8s __attribute__((ext_vector_type(8)));
typedef float v4f __attribute__((ext_vector_type(4)));
typedef float v8f __attribute__((ext_vector_type(8)));
typedef unsigned short u16;

__device__ __forceinline__ v4f mfma_bf16(v8s a, v8s b, v4f c) {
  return __builtin_amdgcn_mfma_f32_16x16x32_bf16(a, b, c, 0, 0, 0);
}
__device__ __forceinline__ float bf2f(u16 x) {
  union { unsigned int u; float f; } cv; cv.u = ((unsigned int)x) << 16; return cv.f;
}
__device__ __forceinline__ u16 f2bf(float f) {
  union { float f; unsigned int u; } cv; cv.f = f;
  unsigned int r = cv.u + 0x7FFFu + ((cv.u >> 16) & 1u);
  return (u16)(r >> 16);
}
__device__ __forceinline__ void cvt8(const float* p, v8s& hi, v8s& lo) {
  v8f x = *reinterpret_cast<const v8f*>(p);
#pragma unroll
  for (int j = 0; j < 8; ++j) {
    u16 h = f2bf(x[j]);
    hi[j] = (short)h;
    lo[j] = (short)f2bf(x[j] - bf2f(h));
  }
}
__device__ __forceinline__ v8s cvt8h(const float* p) {
  v8f x = *reinterpret_cast<const v8f*>(p);
  v8s h;
#pragma unroll
  for (int j = 0; j < 8; ++j) h[j] = (short)f2bf(x[j]);
  return h;
}

// Y[4096,1024] = X @ W^T + bias (f32 in), 3-term bf16 split GEMM, bf16 out
// in [b,h,l,d] layout (workspace intermediate).
__global__ __launch_bounds__(512) void proj_qk3(
    const float* __restrict__ X, const float* __restrict__ W,
    const float* __restrict__ bias, u16* __restrict__ out) {
  const int tid = threadIdx.x;
  const int wv = tid >> 6;
  const int l = tid & 63;
  const int lo4 = l & 15, hi2 = l >> 4;
  const int row0 = blockIdx.x * 16;
  const int col0 = wv * 128;
  v4f acc[8];
#pragma unroll
  for (int i = 0; i < 8; ++i) acc[i] = (v4f){0.f, 0.f, 0.f, 0.f};
  const float* xrow = X + (row0 + lo4) * DM + hi2 * 8;
  for (int ks = 0; ks < 32; ++ks) {
    v8s ah, al;
    cvt8(xrow + ks * 32, ah, al);
#pragma unroll
    for (int kt = 0; kt < 8; ++kt) {
      const float* bp = W + (col0 + kt * 16 + lo4) * DM + ks * 32 + hi2 * 8;
      v8s bh_, bl_;
      cvt8(bp, bh_, bl_);
      acc[kt] = mfma_bf16(ah, bh_, acc[kt]);
      acc[kt] = mfma_bf16(ah, bl_, acc[kt]);
      acc[kt] = mfma_bf16(al, bh_, acc[kt]);
    }
  }
#pragma unroll
  for (int kt = 0; kt < 8; ++kt) {
#pragma unroll
    for (int r = 0; r < 4; ++r) {
      int row = row0 + hi2 * 4 + r;
      int col = col0 + kt * 16 + lo4;
      float v = acc[kt][r] + bias[col];
      int b_ = row >> 10, pos = row & (SL - 1);
      int h = col >> 6, d = col & (HD - 1);
      out[((b_ * NH + h) * SL + pos) * HD + d] = f2bf(v);
    }
  }
}

// V projection: single bf16 term, output TRANSPOSED [b,h,d,l] (workspace).
__global__ __launch_bounds__(512) void proj_v(
    const float* __restrict__ X, const float* __restrict__ W,
    const float* __restrict__ bias, u16* __restrict__ vt) {
  const int tid = threadIdx.x;
  const int wv = tid >> 6;
  const int l = tid & 63;
  const int lo4 = l & 15, hi2 = l >> 4;
  const int row0 = blockIdx.x * 16;
  const int col0 = wv * 128;
  v4f acc[8];
#pragma unroll
  for (int i = 0; i < 8; ++i) acc[i] = (v4f){0.f, 0.f, 0.f, 0.f};
  const float* xrow = X + (row0 + lo4) * DM + hi2 * 8;
  for (int ks = 0; ks < 32; ++ks) {
    v8s a = cvt8h(xrow + ks * 32);
#pragma unroll
    for (int kt = 0; kt < 8; ++kt) {
      const float* bp = W + (col0 + kt * 16 + lo4) * DM + ks * 32 + hi2 * 8;
      v8s b = cvt8h(bp);
      acc[kt] = mfma_bf16(a, b, acc[kt]);
    }
  }
#pragma unroll
  for (int kt = 0; kt < 8; ++kt) {
#pragma unroll
    for (int r = 0; r < 4; ++r) {
      int row = row0 + hi2 * 4 + r;
      int col = col0 + kt * 16 + lo4;
      float v = acc[kt][r] + bias[col];
      int b_ = row >> 10, pos = row & (SL - 1);
      int h = col >> 6, d = col & (HD - 1);
      vt[(((b_ * NH + h) * HD + d) * SL) + pos] = f2bf(v);
    }
  }
}

// One block: one (b,h), 16 query rows. Exact softmax. Writes P as FLOAT32 to
// d_out attn region (+ bf16 copy to LDS), then PV -> ctx (FLOAT32, in out0).
__global__ __launch_bounds__(256) void attn_kernel(
    const u16* __restrict__ qh, const u16* __restrict__ kh,
    const u16* __restrict__ vt, const int* __restrict__ seq_len,
    float* __restrict__ attn_out, float* __restrict__ ctx) {
  const int bh = blockIdx.x;
  const int qt = blockIdx.y;
  const int b_ = bh >> 4, h = bh & 15;
  const int seqb = seq_len[b_];
  const int tid = threadIdx.x;
  const int wv = tid >> 6, l = tid & 63;
  const int lo4 = l & 15, hi2 = l >> 4;

  __shared__ u16 p_lds[16][1032];
  __shared__ float red_m[4][16];
  __shared__ float red_s[4][16];

  const u16* qp = qh + ((size_t)bh * SL + qt * 16 + lo4) * HD + hi2 * 8;
  v8s aq0 = *(const v8s*)(qp);
  v8s aq1 = *(const v8s*)(qp + 32);

  const int kbase = wv * 256;
  const u16* Kb = kh + (size_t)bh * SL * HD;

  v4f s[16];
#pragma unroll
  for (int kt = 0; kt < 16; ++kt) {
    int key = kbase + kt * 16 + lo4;
    const u16* kp = Kb + key * HD + hi2 * 8;
    v8s bk0 = *(const v8s*)kp;
    v8s bk1 = *(const v8s*)(kp + 32);
    v4f acc = (v4f){0.f, 0.f, 0.f, 0.f};
    acc = mfma_bf16(aq0, bk0, acc);
    acc = mfma_bf16(aq1, bk1, acc);
    bool km = key >= seqb;
#pragma unroll
    for (int r = 0; r < 4; ++r)
      s[kt][r] = km ? -INFINITY : acc[r] * 0.125f;
  }

  float m[4];
#pragma unroll
  for (int r = 0; r < 4; ++r) {
    float mm = s[0][r];
#pragma unroll
    for (int kt = 1; kt < 16; ++kt) mm = fmaxf(mm, s[kt][r]);
    for (int d2 = 1; d2 < 16; d2 <<= 1) mm = fmaxf(mm, __shfl_xor(mm, d2));
    m[r] = mm;
  }
  if (lo4 == 0) {
#pragma unroll
    for (int r = 0; r < 4; ++r) red_m[wv][hi2 * 4 + r] = m[r];
  }
  __syncthreads();
#pragma unroll
  for (int r = 0; r < 4; ++r) {
    float mm = red_m[0][hi2 * 4 + r];
    mm = fmaxf(mm, red_m[1][hi2 * 4 + r]);
    mm = fmaxf(mm, red_m[2][hi2 * 4 + r]);
    mm = fmaxf(mm, red_m[3][hi2 * 4 + r]);
    m[r] = mm;
  }
  float sm[4] = {0.f, 0.f, 0.f, 0.f};
#pragma unroll
  for (int kt = 0; kt < 16; ++kt) {
#pragma unroll
    for (int r = 0; r < 4; ++r) {
      float p = expf(s[kt][r] - m[r]);
      s[kt][r] = p;
      sm[r] += p;
    }
  }
#pragma unroll
  for (int r = 0; r < 4; ++r)
    for (int d2 = 1; d2 < 16; d2 <<= 1) sm[r] += __shfl_xor(sm[r], d2);
  if (lo4 == 0) {
#pragma unroll
    for (int r = 0; r < 4; ++r) red_s[wv][hi2 * 4 + r] = sm[r];
  }
  __syncthreads();
  float inv[4];
#pragma unroll
  for (int r = 0; r < 4; ++r) {
    float t = red_s[0][hi2 * 4 + r] + red_s[1][hi2 * 4 + r] +
              red_s[2][hi2 * 4 + r] + red_s[3][hi2 * 4 + r];
    inv[r] = 1.f / t;
  }
  float* aout = attn_out + ((size_t)(h * NB + b_) * SL + qt * 16) * SL;
#pragma unroll
  for (int r = 0; r < 4; ++r) {
    int row = hi2 * 4 + r;
    bool qm = (qt * 16 + row) >= seqb;
    float sc = qm ? 0.f : inv[r];
#pragma unroll
    for (int kt = 0; kt < 16; ++kt) {
      int key = kbase + kt * 16 + lo4;
      float p = s[kt][r] * sc;
      aout[(size_t)row * SL + key] = p;      // FLOAT32 output
      p_lds[row][key] = f2bf(p);             // bf16 copy for PV MFMA
    }
  }
  __syncthreads();
  v4f o = (v4f){0.f, 0.f, 0.f, 0.f};
  const u16* vbase = vt + (size_t)bh * HD * SL + (wv * 16 + lo4) * SL + hi2 * 8;
#pragma unroll 8
  for (int c = 0; c < 32; ++c) {
    v8s pa = *(const v8s*)&p_lds[lo4][c * 32 + hi2 * 8];
    v8s vb = *(const v8s*)(vbase + c * 32);
    o = mfma_bf16(pa, vb, o);
  }
#pragma unroll
  for (int r = 0; r < 4; ++r) {
    int row = qt * 16 + hi2 * 4 + r;
    ctx[((size_t)b_ * SL + row) * DM + h * HD + wv * 16 + lo4] = o[r];  // f32
  }
}

// out = LayerNorm(ctx @ fc_w^T + fc_b + q_raw). ctx is FLOAT32 (in out0
// region, in-place safe: all reads precede the barrier), out is FLOAT32.
__global__ __launch_bounds__(512) void fc_ln(
    const float* __restrict__ ctx, const float* __restrict__ fcw,
    const float* __restrict__ fcb, const float* __restrict__ residual,
    const float* __restrict__ lng, const float* __restrict__ lnb,
    float* __restrict__ out) {
  const int tid = threadIdx.x;
  const int wv = tid >> 6, l = tid & 63;
  const int lo4 = l & 15, hi2 = l >> 4;
  const int row0 = blockIdx.x * 16;
  const int col0 = wv * 128;
  __shared__ float red[2][8][16];
  v4f acc[8];
#pragma unroll
  for (int i = 0; i < 8; ++i) acc[i] = (v4f){0.f, 0.f, 0.f, 0.f};
  const float* arow = ctx + ((size_t)row0 + lo4) * DM + hi2 * 8;
  for (int ks = 0; ks < 32; ++ks) {
    v8s a = cvt8h(arow + ks * 32);
#pragma unroll
    for (int kt = 0; kt < 8; ++kt) {
      const float* bp = fcw + (col0 + kt * 16 + lo4) * DM + ks * 32 + hi2 * 8;
      v8s b = cvt8h(bp);
      acc[kt] = mfma_bf16(a, b, acc[kt]);
    }
  }
  float sm[4] = {0.f, 0.f, 0.f, 0.f}, sq[4] = {0.f, 0.f, 0.f, 0.f};
#pragma unroll
  for (int kt = 0; kt < 8; ++kt) {
#pragma unroll
    for (int r = 0; r < 4; ++r) {
      int col = col0 + kt * 16 + lo4;
      int row = row0 + hi2 * 4 + r;
      float v = acc[kt][r] + fcb[col] + residual[(size_t)row * DM + col];
      acc[kt][r] = v;
      sm[r] += v;
      sq[r] += v * v;
    }
  }
#pragma unroll
  for (int r = 0; r < 4; ++r) {
    for (int d2 = 1; d2 < 16; d2 <<= 1) {
      sm[r] += __shfl_xor(sm[r], d2);
      sq[r] += __shfl_xor(sq[r], d2);
    }
  }
  if (lo4 == 0) {
#pragma unroll
    for (int r = 0; r < 4; ++r) {
      red[0][wv][hi2 * 4 + r] = sm[r];
      red[1][wv][hi2 * 4 + r] = sq[r];
    }
  }
  __syncthreads();
#pragma unroll
  for (int r = 0; r < 4; ++r) {
    float S = 0.f, Q = 0.f;
#pragma unroll
    for (int w2 = 0; w2 < 8; ++w2) {
      S += red[0][w2][hi2 * 4 + r];
      Q += red[1][w2][hi2 * 4 + r];
    }
    float mean = S * (1.f / DM);
    float var = Q * (1.f / DM) - mean * mean;
    float rstd = rsqrtf(var + 1e-5f);
#pragma unroll
    for (int kt = 0; kt < 8; ++kt) {
      int col = col0 + kt * 16 + lo4;
      int row = row0 + hi2 * 4 + r;
      float y = (acc[kt][r] - mean) * rstd * lng[col] + lnb[col];
      out[(size_t)row * DM + col] = y;   // FLOAT32 output
    }
  }
}

extern "C" void kernel_launch(void* const* d_in, const int* in_sizes, int n_in,
                              void* d_out, int out_size, void* d_ws, size_t ws_size,
                              hipStream_t stream) {
  const float* q = (const float*)d_in[0];
  const float* k = (const float*)d_in[1];
  const float* v = (const float*)d_in[2];
  const int* seq_len = (const int*)d_in[3];
  const float* w_qs = (const float*)d_in[4];
  const float* b_qs = (const float*)d_in[5];
  const float* w_ks = (const float*)d_in[6];
  const float* b_ks = (const float*)d_in[7];
  const float* w_vs = (const float*)d_in[8];
  const float* b_vs = (const float*)d_in[9];
  const float* fcw = (const float*)d_in[10];
  const float* fcb = (const float*)d_in[11];
  const float* lng = (const float*)d_in[12];
  const float* lnb = (const float*)d_in[13];

  float* out0 = (float*)d_out;                       // FLOAT32 output buffer
  float* attn_out = out0 + (size_t)NB * SL * DM;     // f32 attn region

  const size_t PLANE = (size_t)NB * SL * DM;
  u16* ws = (u16*)d_ws;
  u16* qh = ws;               // 8 MB bf16
  u16* kh = ws + PLANE;       // 8 MB
  u16* vt = ws + 2 * PLANE;   // 8 MB -> 24 MB total
  float* ctx = out0;          // f32 ctx in out0 region; fc_ln in-place

  proj_qk3<<<256, 512, 0, stream>>>(q, w_qs, b_qs, qh);
  proj_qk3<<<256, 512, 0, stream>>>(k, w_ks, b_ks, kh);
  proj_v<<<256, 512, 0, stream>>>(v, w_vs, b_vs, vt);
  attn_kernel<<<dim3(64, 64), 256, 0, stream>>>(qh, kh, vt, seq_len, attn_out, ctx);
  fc_ln<<<256, 512, 0, stream>>>(ctx, fcw, fcb, q, lng, lnb, out0);
}

// Round 22
// 472.643 us; speedup vs baseline: 1.5809x; 1.5809x over previous
//
#include <hip/hip_runtime.h>
#include <math.h>

#define NB 4
#define SL 1024
#define DM 1024
#define NH 16
#define HD 64

typedef short v8s __attribute__((ext_vector_type(8)));
typedef float v4f __attribute__((ext_vector_type(4)));
typedef unsigned short u16;

__device__ __forceinline__ v4f mfma_bf16(v8s a, v8s b, v4f c) {
  return __builtin_amdgcn_mfma_f32_16x16x32_bf16(a, b, c, 0, 0, 0);
}
__device__ __forceinline__ float bf2f(u16 x) {
  union { unsigned int u; float f; } cv; cv.u = ((unsigned int)x) << 16; return cv.f;
}
__device__ __forceinline__ u16 f2bf(float f) {
  union { float f; unsigned int u; } cv; cv.f = f;
  unsigned int r = cv.u + 0x7FFFu + ((cv.u >> 16) & 1u);
  return (u16)(r >> 16);
}
__device__ __forceinline__ v8s cvt8h(const float* p) {
  v8s h;
#pragma unroll
  for (int j = 0; j < 8; ++j) h[j] = (short)f2bf(p[j]);
  return h;
}

// ---------- pre-convert kernels (memory-bound, run once) ----------
__global__ __launch_bounds__(256) void cvt_hilo_k(
    const float* __restrict__ in, u16* __restrict__ hi, u16* __restrict__ lo,
    int n) {  // n multiple of 4
  int i = (blockIdx.x * 256 + threadIdx.x) * 4;
  const int stride = gridDim.x * 1024;
  for (; i < n; i += stride) {
    float4 x = *reinterpret_cast<const float4*>(in + i);
    ushort4 h, l;
    h.x = f2bf(x.x); l.x = f2bf(x.x - bf2f(h.x));
    h.y = f2bf(x.y); l.y = f2bf(x.y - bf2f(h.y));
    h.z = f2bf(x.z); l.z = f2bf(x.z - bf2f(h.z));
    h.w = f2bf(x.w); l.w = f2bf(x.w - bf2f(h.w));
    *reinterpret_cast<ushort4*>(hi + i) = h;
    *reinterpret_cast<ushort4*>(lo + i) = l;
  }
}
__global__ __launch_bounds__(256) void cvt_hi_k(
    const float* __restrict__ in, u16* __restrict__ hi, int n) {
  int i = (blockIdx.x * 256 + threadIdx.x) * 4;
  const int stride = gridDim.x * 1024;
  for (; i < n; i += stride) {
    float4 x = *reinterpret_cast<const float4*>(in + i);
    ushort4 h;
    h.x = f2bf(x.x); h.y = f2bf(x.y); h.z = f2bf(x.z); h.w = f2bf(x.w);
    *reinterpret_cast<ushort4*>(hi + i) = h;
  }
}

// ---------- projection GEMMs (pure bf16 loads + MFMA) ----------
// out[b,h,l,d] = (Xh+Xl) @ W^T + bias  (2-term, W single bf16)
__global__ __launch_bounds__(512) void proj2t(
    const u16* __restrict__ Xh, const u16* __restrict__ Xl,
    const u16* __restrict__ Wb, const float* __restrict__ bias,
    u16* __restrict__ out) {
  const int tid = threadIdx.x;
  const int wv = tid >> 6;
  const int l = tid & 63;
  const int lo4 = l & 15, hi2 = l >> 4;
  const int row0 = blockIdx.x * 16;
  const int col0 = wv * 128;
  v4f acc[8];
#pragma unroll
  for (int i = 0; i < 8; ++i) acc[i] = (v4f){0.f, 0.f, 0.f, 0.f};
  const size_t abase = (size_t)(row0 + lo4) * DM + hi2 * 8;
  for (int ks = 0; ks < 32; ++ks) {
    v8s ah = *(const v8s*)(Xh + abase + ks * 32);
    v8s al = *(const v8s*)(Xl + abase + ks * 32);
#pragma unroll
    for (int kt = 0; kt < 8; ++kt) {
      v8s b = *(const v8s*)(Wb + (size_t)(col0 + kt * 16 + lo4) * DM + ks * 32 + hi2 * 8);
      acc[kt] = mfma_bf16(ah, b, acc[kt]);
      acc[kt] = mfma_bf16(al, b, acc[kt]);
    }
  }
#pragma unroll
  for (int kt = 0; kt < 8; ++kt) {
#pragma unroll
    for (int r = 0; r < 4; ++r) {
      int row = row0 + hi2 * 4 + r;
      int col = col0 + kt * 16 + lo4;
      float v = acc[kt][r] + bias[col];
      int b_ = row >> 10, pos = row & (SL - 1);
      int h = col >> 6, d = col & (HD - 1);
      out[((b_ * NH + h) * SL + pos) * HD + d] = f2bf(v);
    }
  }
}

// vt[b,h,d,l] = X @ W^T + bias  (1-term, transposed out)
__global__ __launch_bounds__(512) void proj1t(
    const u16* __restrict__ Xb, const u16* __restrict__ Wb,
    const float* __restrict__ bias, u16* __restrict__ vt) {
  const int tid = threadIdx.x;
  const int wv = tid >> 6;
  const int l = tid & 63;
  const int lo4 = l & 15, hi2 = l >> 4;
  const int row0 = blockIdx.x * 16;
  const int col0 = wv * 128;
  v4f acc[8];
#pragma unroll
  for (int i = 0; i < 8; ++i) acc[i] = (v4f){0.f, 0.f, 0.f, 0.f};
  const size_t abase = (size_t)(row0 + lo4) * DM + hi2 * 8;
  for (int ks = 0; ks < 32; ++ks) {
    v8s a = *(const v8s*)(Xb + abase + ks * 32);
#pragma unroll
    for (int kt = 0; kt < 8; ++kt) {
      v8s b = *(const v8s*)(Wb + (size_t)(col0 + kt * 16 + lo4) * DM + ks * 32 + hi2 * 8);
      acc[kt] = mfma_bf16(a, b, acc[kt]);
    }
  }
#pragma unroll
  for (int kt = 0; kt < 8; ++kt) {
#pragma unroll
    for (int r = 0; r < 4; ++r) {
      int row = row0 + hi2 * 4 + r;
      int col = col0 + kt * 16 + lo4;
      float v = acc[kt][r] + bias[col];
      int b_ = row >> 10, pos = row & (SL - 1);
      int h = col >> 6, d = col & (HD - 1);
      vt[(((b_ * NH + h) * HD + d) * SL) + pos] = f2bf(v);
    }
  }
}

// ---------- attention (unchanged from r21) ----------
__global__ __launch_bounds__(256) void attn_kernel(
    const u16* __restrict__ qh, const u16* __restrict__ kh,
    const u16* __restrict__ vt, const int* __restrict__ seq_len,
    float* __restrict__ attn_out, float* __restrict__ ctx) {
  const int bh = blockIdx.x;
  const int qt = blockIdx.y;
  const int b_ = bh >> 4, h = bh & 15;
  const int seqb = seq_len[b_];
  const int tid = threadIdx.x;
  const int wv = tid >> 6, l = tid & 63;
  const int lo4 = l & 15, hi2 = l >> 4;

  __shared__ u16 p_lds[16][1032];
  __shared__ float red_m[4][16];
  __shared__ float red_s[4][16];

  const u16* qp = qh + ((size_t)bh * SL + qt * 16 + lo4) * HD + hi2 * 8;
  v8s aq0 = *(const v8s*)(qp);
  v8s aq1 = *(const v8s*)(qp + 32);

  const int kbase = wv * 256;
  const u16* Kb = kh + (size_t)bh * SL * HD;

  v4f s[16];
#pragma unroll
  for (int kt = 0; kt < 16; ++kt) {
    int key = kbase + kt * 16 + lo4;
    const u16* kp = Kb + key * HD + hi2 * 8;
    v8s bk0 = *(const v8s*)kp;
    v8s bk1 = *(const v8s*)(kp + 32);
    v4f acc = (v4f){0.f, 0.f, 0.f, 0.f};
    acc = mfma_bf16(aq0, bk0, acc);
    acc = mfma_bf16(aq1, bk1, acc);
    bool km = key >= seqb;
#pragma unroll
    for (int r = 0; r < 4; ++r)
      s[kt][r] = km ? -INFINITY : acc[r] * 0.125f;
  }

  float m[4];
#pragma unroll
  for (int r = 0; r < 4; ++r) {
    float mm = s[0][r];
#pragma unroll
    for (int kt = 1; kt < 16; ++kt) mm = fmaxf(mm, s[kt][r]);
    for (int d2 = 1; d2 < 16; d2 <<= 1) mm = fmaxf(mm, __shfl_xor(mm, d2));
    m[r] = mm;
  }
  if (lo4 == 0) {
#pragma unroll
    for (int r = 0; r < 4; ++r) red_m[wv][hi2 * 4 + r] = m[r];
  }
  __syncthreads();
#pragma unroll
  for (int r = 0; r < 4; ++r) {
    float mm = red_m[0][hi2 * 4 + r];
    mm = fmaxf(mm, red_m[1][hi2 * 4 + r]);
    mm = fmaxf(mm, red_m[2][hi2 * 4 + r]);
    mm = fmaxf(mm, red_m[3][hi2 * 4 + r]);
    m[r] = mm;
  }
  float sm[4] = {0.f, 0.f, 0.f, 0.f};
#pragma unroll
  for (int kt = 0; kt < 16; ++kt) {
#pragma unroll
    for (int r = 0; r < 4; ++r) {
      float p = expf(s[kt][r] - m[r]);
      s[kt][r] = p;
      sm[r] += p;
    }
  }
#pragma unroll
  for (int r = 0; r < 4; ++r)
    for (int d2 = 1; d2 < 16; d2 <<= 1) sm[r] += __shfl_xor(sm[r], d2);
  if (lo4 == 0) {
#pragma unroll
    for (int r = 0; r < 4; ++r) red_s[wv][hi2 * 4 + r] = sm[r];
  }
  __syncthreads();
  float inv[4];
#pragma unroll
  for (int r = 0; r < 4; ++r) {
    float t = red_s[0][hi2 * 4 + r] + red_s[1][hi2 * 4 + r] +
              red_s[2][hi2 * 4 + r] + red_s[3][hi2 * 4 + r];
    inv[r] = 1.f / t;
  }
  float* aout = attn_out + ((size_t)(h * NB + b_) * SL + qt * 16) * SL;
#pragma unroll
  for (int r = 0; r < 4; ++r) {
    int row = hi2 * 4 + r;
    bool qm = (qt * 16 + row) >= seqb;
    float sc = qm ? 0.f : inv[r];
#pragma unroll
    for (int kt = 0; kt < 16; ++kt) {
      int key = kbase + kt * 16 + lo4;
      float p = s[kt][r] * sc;
      aout[(size_t)row * SL + key] = p;
      p_lds[row][key] = f2bf(p);
    }
  }
  __syncthreads();
  v4f o = (v4f){0.f, 0.f, 0.f, 0.f};
  const u16* vbase = vt + (size_t)bh * HD * SL + (wv * 16 + lo4) * SL + hi2 * 8;
#pragma unroll 8
  for (int c = 0; c < 32; ++c) {
    v8s pa = *(const v8s*)&p_lds[lo4][c * 32 + hi2 * 8];
    v8s vb = *(const v8s*)(vbase + c * 32);
    o = mfma_bf16(pa, vb, o);
  }
#pragma unroll
  for (int r = 0; r < 4; ++r) {
    int row = qt * 16 + hi2 * 4 + r;
    ctx[((size_t)b_ * SL + row) * DM + h * HD + wv * 16 + lo4] = o[r];
  }
}

// ---------- fc + residual + LN (fcw pre-converted) ----------
__global__ __launch_bounds__(512) void fc_ln(
    const float* __restrict__ ctx, const u16* __restrict__ fcwb,
    const float* __restrict__ fcb, const float* __restrict__ residual,
    const float* __restrict__ lng, const float* __restrict__ lnb,
    float* __restrict__ out) {
  const int tid = threadIdx.x;
  const int wv = tid >> 6, l = tid & 63;
  const int lo4 = l & 15, hi2 = l >> 4;
  const int row0 = blockIdx.x * 16;
  const int col0 = wv * 128;
  __shared__ float red[2][8][16];
  v4f acc[8];
#pragma unroll
  for (int i = 0; i < 8; ++i) acc[i] = (v4f){0.f, 0.f, 0.f, 0.f};
  const float* arow = ctx + ((size_t)row0 + lo4) * DM + hi2 * 8;
  for (int ks = 0; ks < 32; ++ks) {
    v8s a = cvt8h(arow + ks * 32);
#pragma unroll
    for (int kt = 0; kt < 8; ++kt) {
      v8s b = *(const v8s*)(fcwb + (size_t)(col0 + kt * 16 + lo4) * DM + ks * 32 + hi2 * 8);
      acc[kt] = mfma_bf16(a, b, acc[kt]);
    }
  }
  float sm[4] = {0.f, 0.f, 0.f, 0.f}, sq[4] = {0.f, 0.f, 0.f, 0.f};
#pragma unroll
  for (int kt = 0; kt < 8; ++kt) {
#pragma unroll
    for (int r = 0; r < 4; ++r) {
      int col = col0 + kt * 16 + lo4;
      int row = row0 + hi2 * 4 + r;
      float v = acc[kt][r] + fcb[col] + residual[(size_t)row * DM + col];
      acc[kt][r] = v;
      sm[r] += v;
      sq[r] += v * v;
    }
  }
#pragma unroll
  for (int r = 0; r < 4; ++r) {
    for (int d2 = 1; d2 < 16; d2 <<= 1) {
      sm[r] += __shfl_xor(sm[r], d2);
      sq[r] += __shfl_xor(sq[r], d2);
    }
  }
  if (lo4 == 0) {
#pragma unroll
    for (int r = 0; r < 4; ++r) {
      red[0][wv][hi2 * 4 + r] = sm[r];
      red[1][wv][hi2 * 4 + r] = sq[r];
    }
  }
  __syncthreads();
#pragma unroll
  for (int r = 0; r < 4; ++r) {
    float S = 0.f, Q = 0.f;
#pragma unroll
    for (int w2 = 0; w2 < 8; ++w2) {
      S += red[0][w2][hi2 * 4 + r];
      Q += red[1][w2][hi2 * 4 + r];
    }
    float mean = S * (1.f / DM);
    float var = Q * (1.f / DM) - mean * mean;
    float rstd = rsqrtf(var + 1e-5f);
#pragma unroll
    for (int kt = 0; kt < 8; ++kt) {
      int col = col0 + kt * 16 + lo4;
      int row = row0 + hi2 * 4 + r;
      float y = (acc[kt][r] - mean) * rstd * lng[col] + lnb[col];
      out[(size_t)row * DM + col] = y;
    }
  }
}

extern "C" void kernel_launch(void* const* d_in, const int* in_sizes, int n_in,
                              void* d_out, int out_size, void* d_ws, size_t ws_size,
                              hipStream_t stream) {
  const float* q = (const float*)d_in[0];
  const float* k = (const float*)d_in[1];
  const float* v = (const float*)d_in[2];
  const int* seq_len = (const int*)d_in[3];
  const float* w_qs = (const float*)d_in[4];
  const float* b_qs = (const float*)d_in[5];
  const float* w_ks = (const float*)d_in[6];
  const float* b_ks = (const float*)d_in[7];
  const float* w_vs = (const float*)d_in[8];
  const float* b_vs = (const float*)d_in[9];
  const float* fcw = (const float*)d_in[10];
  const float* fcb = (const float*)d_in[11];
  const float* lng = (const float*)d_in[12];
  const float* lnb = (const float*)d_in[13];

  float* out0 = (float*)d_out;
  float* attn_out = out0 + (size_t)NB * SL * DM;

  const size_t PLANE = (size_t)NB * SL * DM;   // 4M elems
  const size_t WSZ = (size_t)DM * DM;          // 1M elems
  u16* ws = (u16*)d_ws;
  u16* qh = ws;               // 8 MB (dead after attn -> reused for fcwb)
  u16* kh = ws + PLANE;       // 8 MB
  u16* vt = ws + 2 * PLANE;   // 8 MB
  float* ctx = out0;          // f32 ctx in out0; fc_ln in-place

  // scratch inside the (not-yet-written) attn f32 region: 46 MB of 256 MB
  u16* satt = (u16*)attn_out;
  u16* qxh = satt;
  u16* qxl = satt + PLANE;
  u16* kxh = satt + 2 * PLANE;
  u16* kxl = satt + 3 * PLANE;
  u16* vxh = satt + 4 * PLANE;
  u16* wqb = satt + 5 * PLANE;
  u16* wkb = satt + 5 * PLANE + WSZ;
  u16* wvb = satt + 5 * PLANE + 2 * WSZ;
  u16* fcwb = qh;             // written AFTER attn (qh dead), read by fc_ln

  cvt_hilo_k<<<1024, 256, 0, stream>>>(q, qxh, qxl, (int)PLANE);
  cvt_hilo_k<<<1024, 256, 0, stream>>>(k, kxh, kxl, (int)PLANE);
  cvt_hi_k<<<1024, 256, 0, stream>>>(v, vxh, (int)PLANE);
  cvt_hi_k<<<512, 256, 0, stream>>>(w_qs, wqb, (int)WSZ);
  cvt_hi_k<<<512, 256, 0, stream>>>(w_ks, wkb, (int)WSZ);
  cvt_hi_k<<<512, 256, 0, stream>>>(w_vs, wvb, (int)WSZ);

  proj2t<<<256, 512, 0, stream>>>(qxh, qxl, wqb, b_qs, qh);
  proj2t<<<256, 512, 0, stream>>>(kxh, kxl, wkb, b_ks, kh);
  proj1t<<<256, 512, 0, stream>>>(vxh, wvb, b_vs, vt);

  attn_kernel<<<dim3(64, 64), 256, 0, stream>>>(qh, kh, vt, seq_len, attn_out, ctx);

  cvt_hi_k<<<512, 256, 0, stream>>>(fcw, fcwb, (int)WSZ);
  fc_ln<<<256, 512, 0, stream>>>(ctx, fcwb, fcb, q, lng, lnb, out0);
}

// Round 23
// 449.380 us; speedup vs baseline: 1.6628x; 1.0518x over previous
//
#include <hip/hip_runtime.h>
#include <math.h>

#define NB 4
#define SL 1024
#define DM 1024
#define NH 16
#define HD 64

typedef short v8s __attribute__((ext_vector_type(8)));
typedef float v4f __attribute__((ext_vector_type(4)));
typedef unsigned short u16;

__device__ __forceinline__ v4f mfma_bf16(v8s a, v8s b, v4f c) {
  return __builtin_amdgcn_mfma_f32_16x16x32_bf16(a, b, c, 0, 0, 0);
}
__device__ __forceinline__ float bf2f(u16 x) {
  union { unsigned int u; float f; } cv; cv.u = ((unsigned int)x) << 16; return cv.f;
}
__device__ __forceinline__ u16 f2bf(float f) {
  union { float f; unsigned int u; } cv; cv.f = f;
  unsigned int r = cv.u + 0x7FFFu + ((cv.u >> 16) & 1u);
  return (u16)(r >> 16);
}
__device__ __forceinline__ v8s cvt8h(const float* p) {
  v8s h;
#pragma unroll
  for (int j = 0; j < 8; ++j) h[j] = (short)f2bf(p[j]);
  return h;
}

// ---------- merged pre-convert: q,k (hi/lo) + v (hi). 3M float4 units ----------
__global__ __launch_bounds__(256) void cvt_qkv(
    const float* __restrict__ q, const float* __restrict__ k,
    const float* __restrict__ v, u16* __restrict__ qxh, u16* __restrict__ qxl,
    u16* __restrict__ kxh, u16* __restrict__ kxl, u16* __restrict__ vxh) {
  const unsigned total = 3u << 20;  // 3M float4
  for (unsigned g = blockIdx.x * 256 + threadIdx.x; g < total;
       g += gridDim.x * 256) {
    unsigned r = g >> 20, local = g & ((1u << 20) - 1), i = local * 4;
    const float* src = (r == 0) ? q : (r == 1) ? k : v;
    float4 x = *reinterpret_cast<const float4*>(src + i);
    ushort4 h;
    h.x = f2bf(x.x); h.y = f2bf(x.y); h.z = f2bf(x.z); h.w = f2bf(x.w);
    if (r == 0) {
      ushort4 l;
      l.x = f2bf(x.x - bf2f(h.x)); l.y = f2bf(x.y - bf2f(h.y));
      l.z = f2bf(x.z - bf2f(h.z)); l.w = f2bf(x.w - bf2f(h.w));
      *reinterpret_cast<ushort4*>(qxh + i) = h;
      *reinterpret_cast<ushort4*>(qxl + i) = l;
    } else if (r == 1) {
      ushort4 l;
      l.x = f2bf(x.x - bf2f(h.x)); l.y = f2bf(x.y - bf2f(h.y));
      l.z = f2bf(x.z - bf2f(h.z)); l.w = f2bf(x.w - bf2f(h.w));
      *reinterpret_cast<ushort4*>(kxh + i) = h;
      *reinterpret_cast<ushort4*>(kxl + i) = l;
    } else {
      *reinterpret_cast<ushort4*>(vxh + i) = h;
    }
  }
}
// merged weight convert: w_qs,w_ks,w_vs -> bf16 (0.75M float4)
__global__ __launch_bounds__(256) void cvt_w3(
    const float* __restrict__ wq, const float* __restrict__ wk,
    const float* __restrict__ wv, u16* __restrict__ wqb,
    u16* __restrict__ wkb, u16* __restrict__ wvb) {
  const unsigned total = 3u << 18;
  for (unsigned g = blockIdx.x * 256 + threadIdx.x; g < total;
       g += gridDim.x * 256) {
    unsigned r = g >> 18, local = g & ((1u << 18) - 1), i = local * 4;
    const float* src = (r == 0) ? wq : (r == 1) ? wk : wv;
    u16* dst = (r == 0) ? wqb : (r == 1) ? wkb : wvb;
    float4 x = *reinterpret_cast<const float4*>(src + i);
    ushort4 h;
    h.x = f2bf(x.x); h.y = f2bf(x.y); h.z = f2bf(x.z); h.w = f2bf(x.w);
    *reinterpret_cast<ushort4*>(dst + i) = h;
  }
}
__global__ __launch_bounds__(256) void cvt_hi_k(
    const float* __restrict__ in, u16* __restrict__ hi, int n) {
  int i = (blockIdx.x * 256 + threadIdx.x) * 4;
  const int stride = gridDim.x * 1024;
  for (; i < n; i += stride) {
    float4 x = *reinterpret_cast<const float4*>(in + i);
    ushort4 h;
    h.x = f2bf(x.x); h.y = f2bf(x.y); h.z = f2bf(x.z); h.w = f2bf(x.w);
    *reinterpret_cast<ushort4*>(hi + i) = h;
  }
}

// ---------- merged projection GEMM: 768 blocks (q | k | v) ----------
__global__ __launch_bounds__(512) void proj_all(
    const u16* __restrict__ qxh, const u16* __restrict__ qxl,
    const u16* __restrict__ kxh, const u16* __restrict__ kxl,
    const u16* __restrict__ vxh, const u16* __restrict__ wqb,
    const u16* __restrict__ wkb, const u16* __restrict__ wvb,
    const float* __restrict__ b_qs, const float* __restrict__ b_ks,
    const float* __restrict__ b_vs, u16* __restrict__ qh,
    u16* __restrict__ kh, u16* __restrict__ vt) {
  const int bid = blockIdx.x;
  const int sel = bid >> 8;            // 0=q, 1=k, 2=v
  const int row0 = (bid & 255) * 16;
  const int tid = threadIdx.x;
  const int wv = tid >> 6;
  const int l = tid & 63;
  const int lo4 = l & 15, hi2 = l >> 4;
  const int col0 = wv * 128;

  v4f acc[8];
#pragma unroll
  for (int i = 0; i < 8; ++i) acc[i] = (v4f){0.f, 0.f, 0.f, 0.f};
  const size_t abase = (size_t)(row0 + lo4) * DM + hi2 * 8;

  if (sel < 2) {
    const u16* Xh = sel ? kxh : qxh;
    const u16* Xl = sel ? kxl : qxl;
    const u16* Wb = sel ? wkb : wqb;
    for (int ks = 0; ks < 32; ++ks) {
      v8s ah = *(const v8s*)(Xh + abase + ks * 32);
      v8s al = *(const v8s*)(Xl + abase + ks * 32);
#pragma unroll
      for (int kt = 0; kt < 8; ++kt) {
        v8s b = *(const v8s*)(Wb + (size_t)(col0 + kt * 16 + lo4) * DM + ks * 32 + hi2 * 8);
        acc[kt] = mfma_bf16(ah, b, acc[kt]);
        acc[kt] = mfma_bf16(al, b, acc[kt]);
      }
    }
    const float* bias = sel ? b_ks : b_qs;
    u16* out = sel ? kh : qh;
#pragma unroll
    for (int kt = 0; kt < 8; ++kt) {
#pragma unroll
      for (int r = 0; r < 4; ++r) {
        int row = row0 + hi2 * 4 + r;
        int col = col0 + kt * 16 + lo4;
        float vv = acc[kt][r] + bias[col];
        int b_ = row >> 10, pos = row & (SL - 1);
        int h = col >> 6, d = col & (HD - 1);
        out[((b_ * NH + h) * SL + pos) * HD + d] = f2bf(vv);
      }
    }
  } else {
    for (int ks = 0; ks < 32; ++ks) {
      v8s a = *(const v8s*)(vxh + abase + ks * 32);
#pragma unroll
      for (int kt = 0; kt < 8; ++kt) {
        v8s b = *(const v8s*)(wvb + (size_t)(col0 + kt * 16 + lo4) * DM + ks * 32 + hi2 * 8);
        acc[kt] = mfma_bf16(a, b, acc[kt]);
      }
    }
#pragma unroll
    for (int kt = 0; kt < 8; ++kt) {
#pragma unroll
      for (int r = 0; r < 4; ++r) {
        int row = row0 + hi2 * 4 + r;
        int col = col0 + kt * 16 + lo4;
        float vv = acc[kt][r] + b_vs[col];
        int b_ = row >> 10, pos = row & (SL - 1);
        int h = col >> 6, d = col & (HD - 1);
        vt[(((b_ * NH + h) * HD + d) * SL) + pos] = f2bf(vv);
      }
    }
  }
}

// ---------- attention: coalesced float4 P write from LDS ----------
__global__ __launch_bounds__(256) void attn_kernel(
    const u16* __restrict__ qh, const u16* __restrict__ kh,
    const u16* __restrict__ vt, const int* __restrict__ seq_len,
    float* __restrict__ attn_out, float* __restrict__ ctx) {
  const int bh = blockIdx.x;
  const int qt = blockIdx.y;
  const int b_ = bh >> 4, h = bh & 15;
  const int seqb = seq_len[b_];
  const int tid = threadIdx.x;
  const int wv = tid >> 6, l = tid & 63;
  const int lo4 = l & 15, hi2 = l >> 4;

  __shared__ u16 p_lds[16][1032];
  __shared__ float red_m[4][16];
  __shared__ float red_s[4][16];

  const u16* qp = qh + ((size_t)bh * SL + qt * 16 + lo4) * HD + hi2 * 8;
  v8s aq0 = *(const v8s*)(qp);
  v8s aq1 = *(const v8s*)(qp + 32);

  const int kbase = wv * 256;
  const u16* Kb = kh + (size_t)bh * SL * HD;

  v4f s[16];
#pragma unroll
  for (int kt = 0; kt < 16; ++kt) {
    int key = kbase + kt * 16 + lo4;
    const u16* kp = Kb + key * HD + hi2 * 8;
    v8s bk0 = *(const v8s*)kp;
    v8s bk1 = *(const v8s*)(kp + 32);
    v4f acc = (v4f){0.f, 0.f, 0.f, 0.f};
    acc = mfma_bf16(aq0, bk0, acc);
    acc = mfma_bf16(aq1, bk1, acc);
    bool km = key >= seqb;
#pragma unroll
    for (int r = 0; r < 4; ++r)
      s[kt][r] = km ? -INFINITY : acc[r] * 0.125f;
  }

  float m[4];
#pragma unroll
  for (int r = 0; r < 4; ++r) {
    float mm = s[0][r];
#pragma unroll
    for (int kt = 1; kt < 16; ++kt) mm = fmaxf(mm, s[kt][r]);
    for (int d2 = 1; d2 < 16; d2 <<= 1) mm = fmaxf(mm, __shfl_xor(mm, d2));
    m[r] = mm;
  }
  if (lo4 == 0) {
#pragma unroll
    for (int r = 0; r < 4; ++r) red_m[wv][hi2 * 4 + r] = m[r];
  }
  __syncthreads();
#pragma unroll
  for (int r = 0; r < 4; ++r) {
    float mm = red_m[0][hi2 * 4 + r];
    mm = fmaxf(mm, red_m[1][hi2 * 4 + r]);
    mm = fmaxf(mm, red_m[2][hi2 * 4 + r]);
    mm = fmaxf(mm, red_m[3][hi2 * 4 + r]);
    m[r] = mm;
  }
  float sm[4] = {0.f, 0.f, 0.f, 0.f};
#pragma unroll
  for (int kt = 0; kt < 16; ++kt) {
#pragma unroll
    for (int r = 0; r < 4; ++r) {
      float p = expf(s[kt][r] - m[r]);
      s[kt][r] = p;
      sm[r] += p;
    }
  }
#pragma unroll
  for (int r = 0; r < 4; ++r)
    for (int d2 = 1; d2 < 16; d2 <<= 1) sm[r] += __shfl_xor(sm[r], d2);
  if (lo4 == 0) {
#pragma unroll
    for (int r = 0; r < 4; ++r) red_s[wv][hi2 * 4 + r] = sm[r];
  }
  __syncthreads();
  float inv[4];
#pragma unroll
  for (int r = 0; r < 4; ++r) {
    float t = red_s[0][hi2 * 4 + r] + red_s[1][hi2 * 4 + r] +
              red_s[2][hi2 * 4 + r] + red_s[3][hi2 * 4 + r];
    inv[r] = 1.f / t;
  }
  // normalize into LDS (bf16) only — coalesced global write afterwards
#pragma unroll
  for (int r = 0; r < 4; ++r) {
    int row = hi2 * 4 + r;
    bool qm = (qt * 16 + row) >= seqb;
    float sc = qm ? 0.f : inv[r];
#pragma unroll
    for (int kt = 0; kt < 16; ++kt) {
      int key = kbase + kt * 16 + lo4;
      p_lds[row][key] = f2bf(s[kt][r] * sc);
    }
  }
  __syncthreads();
  // coalesced float4 P write: 16 rows x 1024 keys
  float* aout = attn_out + ((size_t)(h * NB + b_) * SL + qt * 16) * SL;
#pragma unroll
  for (int i = 0; i < 16; ++i) {
    int idx = (tid + i * 256) * 4;
    int row = idx >> 10, key = idx & 1023;
    ushort4 pv = *(const ushort4*)&p_lds[row][key];
    float4 o4 = make_float4(bf2f(pv.x), bf2f(pv.y), bf2f(pv.z), bf2f(pv.w));
    *reinterpret_cast<float4*>(&aout[(size_t)row * SL + key]) = o4;
  }
  // PV
  v4f o = (v4f){0.f, 0.f, 0.f, 0.f};
  const u16* vbase = vt + (size_t)bh * HD * SL + (wv * 16 + lo4) * SL + hi2 * 8;
#pragma unroll 8
  for (int c = 0; c < 32; ++c) {
    v8s pa = *(const v8s*)&p_lds[lo4][c * 32 + hi2 * 8];
    v8s vb = *(const v8s*)(vbase + c * 32);
    o = mfma_bf16(pa, vb, o);
  }
#pragma unroll
  for (int r = 0; r < 4; ++r) {
    int row = qt * 16 + hi2 * 4 + r;
    ctx[((size_t)b_ * SL + row) * DM + h * HD + wv * 16 + lo4] = o[r];
  }
}

// ---------- fc + residual + LN ----------
__global__ __launch_bounds__(512) void fc_ln(
    const float* __restrict__ ctx, const u16* __restrict__ fcwb,
    const float* __restrict__ fcb, const float* __restrict__ residual,
    const float* __restrict__ lng, const float* __restrict__ lnb,
    float* __restrict__ out) {
  const int tid = threadIdx.x;
  const int wv = tid >> 6, l = tid & 63;
  const int lo4 = l & 15, hi2 = l >> 4;
  const int row0 = blockIdx.x * 16;
  const int col0 = wv * 128;
  __shared__ float red[2][8][16];
  v4f acc[8];
#pragma unroll
  for (int i = 0; i < 8; ++i) acc[i] = (v4f){0.f, 0.f, 0.f, 0.f};
  const float* arow = ctx + ((size_t)row0 + lo4) * DM + hi2 * 8;
  for (int ks = 0; ks < 32; ++ks) {
    v8s a = cvt8h(arow + ks * 32);
#pragma unroll
    for (int kt = 0; kt < 8; ++kt) {
      v8s b = *(const v8s*)(fcwb + (size_t)(col0 + kt * 16 + lo4) * DM + ks * 32 + hi2 * 8);
      acc[kt] = mfma_bf16(a, b, acc[kt]);
    }
  }
  float sm[4] = {0.f, 0.f, 0.f, 0.f}, sq[4] = {0.f, 0.f, 0.f, 0.f};
#pragma unroll
  for (int kt = 0; kt < 8; ++kt) {
#pragma unroll
    for (int r = 0; r < 4; ++r) {
      int col = col0 + kt * 16 + lo4;
      int row = row0 + hi2 * 4 + r;
      float v = acc[kt][r] + fcb[col] + residual[(size_t)row * DM + col];
      acc[kt][r] = v;
      sm[r] += v;
      sq[r] += v * v;
    }
  }
#pragma unroll
  for (int r = 0; r < 4; ++r) {
    for (int d2 = 1; d2 < 16; d2 <<= 1) {
      sm[r] += __shfl_xor(sm[r], d2);
      sq[r] += __shfl_xor(sq[r], d2);
    }
  }
  if (lo4 == 0) {
#pragma unroll
    for (int r = 0; r < 4; ++r) {
      red[0][wv][hi2 * 4 + r] = sm[r];
      red[1][wv][hi2 * 4 + r] = sq[r];
    }
  }
  __syncthreads();
#pragma unroll
  for (int r = 0; r < 4; ++r) {
    float S = 0.f, Q = 0.f;
#pragma unroll
    for (int w2 = 0; w2 < 8; ++w2) {
      S += red[0][w2][hi2 * 4 + r];
      Q += red[1][w2][hi2 * 4 + r];
    }
    float mean = S * (1.f / DM);
    float var = Q * (1.f / DM) - mean * mean;
    float rstd = rsqrtf(var + 1e-5f);
#pragma unroll
    for (int kt = 0; kt < 8; ++kt) {
      int col = col0 + kt * 16 + lo4;
      int row = row0 + hi2 * 4 + r;
      float y = (acc[kt][r] - mean) * rstd * lng[col] + lnb[col];
      out[(size_t)row * DM + col] = y;
    }
  }
}

extern "C" void kernel_launch(void* const* d_in, const int* in_sizes, int n_in,
                              void* d_out, int out_size, void* d_ws, size_t ws_size,
                              hipStream_t stream) {
  const float* q = (const float*)d_in[0];
  const float* k = (const float*)d_in[1];
  const float* v = (const float*)d_in[2];
  const int* seq_len = (const int*)d_in[3];
  const float* w_qs = (const float*)d_in[4];
  const float* b_qs = (const float*)d_in[5];
  const float* w_ks = (const float*)d_in[6];
  const float* b_ks = (const float*)d_in[7];
  const float* w_vs = (const float*)d_in[8];
  const float* b_vs = (const float*)d_in[9];
  const float* fcw = (const float*)d_in[10];
  const float* fcb = (const float*)d_in[11];
  const float* lng = (const float*)d_in[12];
  const float* lnb = (const float*)d_in[13];

  float* out0 = (float*)d_out;
  float* attn_out = out0 + (size_t)NB * SL * DM;

  const size_t PLANE = (size_t)NB * SL * DM;   // 4M elems
  const size_t WSZ = (size_t)DM * DM;          // 1M elems
  u16* ws = (u16*)d_ws;
  u16* qh = ws;               // 8 MB (dead after attn -> reused for fcwb)
  u16* kh = ws + PLANE;
  u16* vt = ws + 2 * PLANE;
  float* ctx = out0;

  // scratch inside the not-yet-written attn f32 region (46 MB of 256 MB)
  u16* satt = (u16*)attn_out;
  u16* qxh = satt;
  u16* qxl = satt + PLANE;
  u16* kxh = satt + 2 * PLANE;
  u16* kxl = satt + 3 * PLANE;
  u16* vxh = satt + 4 * PLANE;
  u16* wqb = satt + 5 * PLANE;
  u16* wkb = satt + 5 * PLANE + WSZ;
  u16* wvb = satt + 5 * PLANE + 2 * WSZ;
  u16* fcwb = qh;             // written AFTER attn, read by fc_ln

  cvt_qkv<<<3072, 256, 0, stream>>>(q, k, v, qxh, qxl, kxh, kxl, vxh);
  cvt_w3<<<768, 256, 0, stream>>>(w_qs, w_ks, w_vs, wqb, wkb, wvb);
  proj_all<<<768, 512, 0, stream>>>(qxh, qxl, kxh, kxl, vxh, wqb, wkb, wvb,
                                    b_qs, b_ks, b_vs, qh, kh, vt);
  attn_kernel<<<dim3(64, 64), 256, 0, stream>>>(qh, kh, vt, seq_len, attn_out, ctx);
  cvt_hi_k<<<512, 256, 0, stream>>>(fcw, fcwb, (int)WSZ);
  fc_ln<<<256, 512, 0, stream>>>(ctx, fcwb, fcb, q, lng, lnb, out0);
}

// Round 24
// 280.537 us; speedup vs baseline: 2.6635x; 1.6019x over previous
//
#include <hip/hip_runtime.h>
#include <math.h>

#define NB 4
#define SL 1024
#define DM 1024
#define NH 16
#define HD 64

typedef short v8s __attribute__((ext_vector_type(8)));
typedef float v4f __attribute__((ext_vector_type(4)));
typedef float v8f __attribute__((ext_vector_type(8)));
typedef unsigned short u16;

__device__ __forceinline__ v4f mfma_bf16(v8s a, v8s b, v4f c) {
  return __builtin_amdgcn_mfma_f32_16x16x32_bf16(a, b, c, 0, 0, 0);
}
__device__ __forceinline__ float bf2f(u16 x) {
  union { unsigned int u; float f; } cv; cv.u = ((unsigned int)x) << 16; return cv.f;
}
__device__ __forceinline__ u16 f2bf(float f) {
  union { float f; unsigned int u; } cv; cv.f = f;
  unsigned int r = cv.u + 0x7FFFu + ((cv.u >> 16) & 1u);
  return (u16)(r >> 16);
}
__device__ __forceinline__ v8s cvt8h(const float* p) {
  v8f x = *reinterpret_cast<const v8f*>(p);
  v8s h;
#pragma unroll
  for (int j = 0; j < 8; ++j) h[j] = (short)f2bf(x[j]);
  return h;
}

// ---------- merged pre-convert: q,k (hi/lo) + v (hi) ----------
__global__ __launch_bounds__(256) void cvt_qkv(
    const float* __restrict__ q, const float* __restrict__ k,
    const float* __restrict__ v, u16* __restrict__ qxh, u16* __restrict__ qxl,
    u16* __restrict__ kxh, u16* __restrict__ kxl, u16* __restrict__ vxh) {
  const unsigned total = 3u << 20;
  for (unsigned g = blockIdx.x * 256 + threadIdx.x; g < total;
       g += gridDim.x * 256) {
    unsigned r = g >> 20, local = g & ((1u << 20) - 1), i = local * 4;
    const float* src = (r == 0) ? q : (r == 1) ? k : v;
    float4 x = *reinterpret_cast<const float4*>(src + i);
    ushort4 h;
    h.x = f2bf(x.x); h.y = f2bf(x.y); h.z = f2bf(x.z); h.w = f2bf(x.w);
    if (r == 0) {
      ushort4 l;
      l.x = f2bf(x.x - bf2f(h.x)); l.y = f2bf(x.y - bf2f(h.y));
      l.z = f2bf(x.z - bf2f(h.z)); l.w = f2bf(x.w - bf2f(h.w));
      *reinterpret_cast<ushort4*>(qxh + i) = h;
      *reinterpret_cast<ushort4*>(qxl + i) = l;
    } else if (r == 1) {
      ushort4 l;
      l.x = f2bf(x.x - bf2f(h.x)); l.y = f2bf(x.y - bf2f(h.y));
      l.z = f2bf(x.z - bf2f(h.z)); l.w = f2bf(x.w - bf2f(h.w));
      *reinterpret_cast<ushort4*>(kxh + i) = h;
      *reinterpret_cast<ushort4*>(kxl + i) = l;
    } else {
      *reinterpret_cast<ushort4*>(vxh + i) = h;
    }
  }
}
__global__ __launch_bounds__(256) void cvt_w3(
    const float* __restrict__ wq, const float* __restrict__ wk,
    const float* __restrict__ wv, u16* __restrict__ wqb,
    u16* __restrict__ wkb, u16* __restrict__ wvb) {
  const unsigned total = 3u << 18;
  for (unsigned g = blockIdx.x * 256 + threadIdx.x; g < total;
       g += gridDim.x * 256) {
    unsigned r = g >> 18, local = g & ((1u << 18) - 1), i = local * 4;
    const float* src = (r == 0) ? wq : (r == 1) ? wk : wv;
    u16* dst = (r == 0) ? wqb : (r == 1) ? wkb : wvb;
    float4 x = *reinterpret_cast<const float4*>(src + i);
    ushort4 h;
    h.x = f2bf(x.x); h.y = f2bf(x.y); h.z = f2bf(x.z); h.w = f2bf(x.w);
    *reinterpret_cast<ushort4*>(dst + i) = h;
  }
}
__global__ __launch_bounds__(256) void cvt_hi_k(
    const float* __restrict__ in, u16* __restrict__ hi, int n) {
  int i = (blockIdx.x * 256 + threadIdx.x) * 4;
  const int stride = gridDim.x * 1024;
  for (; i < n; i += stride) {
    float4 x = *reinterpret_cast<const float4*>(in + i);
    ushort4 h;
    h.x = f2bf(x.x); h.y = f2bf(x.y); h.z = f2bf(x.z); h.w = f2bf(x.w);
    *reinterpret_cast<ushort4*>(hi + i) = h;
  }
}

// ---------- LDS-tiled 128x128 projection GEMM (q 2t | k 2t | v 1t) ----------
__global__ __launch_bounds__(256) void gemm_proj(
    const u16* __restrict__ qxh, const u16* __restrict__ qxl,
    const u16* __restrict__ kxh, const u16* __restrict__ kxl,
    const u16* __restrict__ vxh, const u16* __restrict__ wqb,
    const u16* __restrict__ wkb, const u16* __restrict__ wvb,
    const float* __restrict__ b_qs, const float* __restrict__ b_ks,
    const float* __restrict__ b_vs, u16* __restrict__ qh,
    u16* __restrict__ kh, u16* __restrict__ vt) {
  __shared__ u16 Ah[128][56];
  __shared__ u16 Al[128][56];
  __shared__ u16 Bt[128][56];
  const int bid = blockIdx.x;
  const int sel = bid >> 8;                // 0=q,1=k,2=v
  const int tb = bid & 255;
  const int row0 = (tb >> 3) * 128;
  const int col0 = (tb & 7) * 128;
  const u16* Xh = (sel == 0) ? qxh : (sel == 1) ? kxh : vxh;
  const u16* Xl = (sel == 1) ? kxl : qxl;
  const u16* Wb = (sel == 0) ? wqb : (sel == 1) ? wkb : wvb;
  const bool two = (sel < 2);

  const int tid = threadIdx.x;
  const int wid = tid >> 6, l = tid & 63, lo4 = l & 15, hi2 = l >> 4;
  const int wm = wid >> 1, wn = wid & 1;

  v4f acc[4][4];
#pragma unroll
  for (int i = 0; i < 4; ++i)
#pragma unroll
    for (int j = 0; j < 4; ++j) acc[i][j] = (v4f){0.f, 0.f, 0.f, 0.f};

  for (int ks = 0; ks < 32; ++ks) {
    const int k0 = ks * 32;
#pragma unroll
    for (int i = 0; i < 2; ++i) {
      int idx = tid + i * 256;
      int r = idx >> 2, c8 = (idx & 3) * 8;
      *(v8s*)&Ah[r][c8] = *(const v8s*)(Xh + (size_t)(row0 + r) * DM + k0 + c8);
      if (two)
        *(v8s*)&Al[r][c8] = *(const v8s*)(Xl + (size_t)(row0 + r) * DM + k0 + c8);
      *(v8s*)&Bt[r][c8] = *(const v8s*)(Wb + (size_t)(col0 + r) * DM + k0 + c8);
    }
    __syncthreads();
    v8s af[4], alf[4], bf[4];
#pragma unroll
    for (int mi = 0; mi < 4; ++mi)
      af[mi] = *(const v8s*)&Ah[wm * 64 + mi * 16 + lo4][hi2 * 8];
#pragma unroll
    for (int ni = 0; ni < 4; ++ni)
      bf[ni] = *(const v8s*)&Bt[wn * 64 + ni * 16 + lo4][hi2 * 8];
    if (two) {
#pragma unroll
      for (int mi = 0; mi < 4; ++mi)
        alf[mi] = *(const v8s*)&Al[wm * 64 + mi * 16 + lo4][hi2 * 8];
    }
#pragma unroll
    for (int mi = 0; mi < 4; ++mi)
#pragma unroll
      for (int ni = 0; ni < 4; ++ni) {
        acc[mi][ni] = mfma_bf16(af[mi], bf[ni], acc[mi][ni]);
        if (two) acc[mi][ni] = mfma_bf16(alf[mi], bf[ni], acc[mi][ni]);
      }
    __syncthreads();
  }

  const float* bias = (sel == 0) ? b_qs : (sel == 1) ? b_ks : b_vs;
#pragma unroll
  for (int mi = 0; mi < 4; ++mi)
#pragma unroll
    for (int ni = 0; ni < 4; ++ni)
#pragma unroll
      for (int r = 0; r < 4; ++r) {
        int row = row0 + wm * 64 + mi * 16 + hi2 * 4 + r;
        int col = col0 + wn * 64 + ni * 16 + lo4;
        float vv = acc[mi][ni][r] + bias[col];
        int b_ = row >> 10, pos = row & (SL - 1);
        int h = col >> 6, d = col & (HD - 1);
        if (sel < 2) {
          u16* out = sel ? kh : qh;
          out[((size_t)(b_ * NH + h) * SL + pos) * HD + d] = f2bf(vv);
        } else {
          vt[((size_t)(b_ * NH + h) * HD + d) * SL + pos] = f2bf(vv);
        }
      }
}

// ---------- attention (unchanged) ----------
__global__ __launch_bounds__(256) void attn_kernel(
    const u16* __restrict__ qh, const u16* __restrict__ kh,
    const u16* __restrict__ vt, const int* __restrict__ seq_len,
    float* __restrict__ attn_out, float* __restrict__ ctx) {
  const int bh = blockIdx.x;
  const int qt = blockIdx.y;
  const int b_ = bh >> 4, h = bh & 15;
  const int seqb = seq_len[b_];
  const int tid = threadIdx.x;
  const int wv = tid >> 6, l = tid & 63;
  const int lo4 = l & 15, hi2 = l >> 4;

  __shared__ u16 p_lds[16][1032];
  __shared__ float red_m[4][16];
  __shared__ float red_s[4][16];

  const u16* qp = qh + ((size_t)bh * SL + qt * 16 + lo4) * HD + hi2 * 8;
  v8s aq0 = *(const v8s*)(qp);
  v8s aq1 = *(const v8s*)(qp + 32);

  const int kbase = wv * 256;
  const u16* Kb = kh + (size_t)bh * SL * HD;

  v4f s[16];
#pragma unroll
  for (int kt = 0; kt < 16; ++kt) {
    int key = kbase + kt * 16 + lo4;
    const u16* kp = Kb + key * HD + hi2 * 8;
    v8s bk0 = *(const v8s*)kp;
    v8s bk1 = *(const v8s*)(kp + 32);
    v4f acc = (v4f){0.f, 0.f, 0.f, 0.f};
    acc = mfma_bf16(aq0, bk0, acc);
    acc = mfma_bf16(aq1, bk1, acc);
    bool km = key >= seqb;
#pragma unroll
    for (int r = 0; r < 4; ++r)
      s[kt][r] = km ? -INFINITY : acc[r] * 0.125f;
  }

  float m[4];
#pragma unroll
  for (int r = 0; r < 4; ++r) {
    float mm = s[0][r];
#pragma unroll
    for (int kt = 1; kt < 16; ++kt) mm = fmaxf(mm, s[kt][r]);
    for (int d2 = 1; d2 < 16; d2 <<= 1) mm = fmaxf(mm, __shfl_xor(mm, d2));
    m[r] = mm;
  }
  if (lo4 == 0) {
#pragma unroll
    for (int r = 0; r < 4; ++r) red_m[wv][hi2 * 4 + r] = m[r];
  }
  __syncthreads();
#pragma unroll
  for (int r = 0; r < 4; ++r) {
    float mm = red_m[0][hi2 * 4 + r];
    mm = fmaxf(mm, red_m[1][hi2 * 4 + r]);
    mm = fmaxf(mm, red_m[2][hi2 * 4 + r]);
    mm = fmaxf(mm, red_m[3][hi2 * 4 + r]);
    m[r] = mm;
  }
  float sm[4] = {0.f, 0.f, 0.f, 0.f};
#pragma unroll
  for (int kt = 0; kt < 16; ++kt) {
#pragma unroll
    for (int r = 0; r < 4; ++r) {
      float p = expf(s[kt][r] - m[r]);
      s[kt][r] = p;
      sm[r] += p;
    }
  }
#pragma unroll
  for (int r = 0; r < 4; ++r)
    for (int d2 = 1; d2 < 16; d2 <<= 1) sm[r] += __shfl_xor(sm[r], d2);
  if (lo4 == 0) {
#pragma unroll
    for (int r = 0; r < 4; ++r) red_s[wv][hi2 * 4 + r] = sm[r];
  }
  __syncthreads();
  float inv[4];
#pragma unroll
  for (int r = 0; r < 4; ++r) {
    float t = red_s[0][hi2 * 4 + r] + red_s[1][hi2 * 4 + r] +
              red_s[2][hi2 * 4 + r] + red_s[3][hi2 * 4 + r];
    inv[r] = 1.f / t;
  }
#pragma unroll
  for (int r = 0; r < 4; ++r) {
    int row = hi2 * 4 + r;
    bool qm = (qt * 16 + row) >= seqb;
    float sc = qm ? 0.f : inv[r];
#pragma unroll
    for (int kt = 0; kt < 16; ++kt) {
      int key = kbase + kt * 16 + lo4;
      p_lds[row][key] = f2bf(s[kt][r] * sc);
    }
  }
  __syncthreads();
  float* aout = attn_out + ((size_t)(h * NB + b_) * SL + qt * 16) * SL;
#pragma unroll
  for (int i = 0; i < 16; ++i) {
    int idx = (tid + i * 256) * 4;
    int row = idx >> 10, key = idx & 1023;
    ushort4 pv = *(const ushort4*)&p_lds[row][key];
    float4 o4 = make_float4(bf2f(pv.x), bf2f(pv.y), bf2f(pv.z), bf2f(pv.w));
    *reinterpret_cast<float4*>(&aout[(size_t)row * SL + key]) = o4;
  }
  v4f o = (v4f){0.f, 0.f, 0.f, 0.f};
  const u16* vbase = vt + (size_t)bh * HD * SL + (wv * 16 + lo4) * SL + hi2 * 8;
#pragma unroll 8
  for (int c = 0; c < 32; ++c) {
    v8s pa = *(const v8s*)&p_lds[lo4][c * 32 + hi2 * 8];
    v8s vb = *(const v8s*)(vbase + c * 32);
    o = mfma_bf16(pa, vb, o);
  }
#pragma unroll
  for (int r = 0; r < 4; ++r) {
    int row = qt * 16 + hi2 * 4 + r;
    ctx[((size_t)b_ * SL + row) * DM + h * HD + wv * 16 + lo4] = o[r];
  }
}

// ---------- LDS-tiled fc GEMM: fcout = ctx @ fcw^T + fcb + residual ----------
__global__ __launch_bounds__(256) void gemm_fc(
    const float* __restrict__ ctx, const u16* __restrict__ fcwb,
    const float* __restrict__ fcb, const float* __restrict__ resid,
    float* __restrict__ fcout) {
  __shared__ u16 At[128][56];
  __shared__ u16 Bt[128][56];
  const int row0 = (blockIdx.x >> 3) * 128;
  const int col0 = (blockIdx.x & 7) * 128;
  const int tid = threadIdx.x;
  const int wid = tid >> 6, l = tid & 63, lo4 = l & 15, hi2 = l >> 4;
  const int wm = wid >> 1, wn = wid & 1;

  v4f acc[4][4];
#pragma unroll
  for (int i = 0; i < 4; ++i)
#pragma unroll
    for (int j = 0; j < 4; ++j) acc[i][j] = (v4f){0.f, 0.f, 0.f, 0.f};

  for (int ks = 0; ks < 32; ++ks) {
    const int k0 = ks * 32;
#pragma unroll
    for (int i = 0; i < 2; ++i) {
      int idx = tid + i * 256;
      int r = idx >> 2, c8 = (idx & 3) * 8;
      *(v8s*)&At[r][c8] = cvt8h(ctx + (size_t)(row0 + r) * DM + k0 + c8);
      *(v8s*)&Bt[r][c8] = *(const v8s*)(fcwb + (size_t)(col0 + r) * DM + k0 + c8);
    }
    __syncthreads();
    v8s af[4], bf[4];
#pragma unroll
    for (int mi = 0; mi < 4; ++mi)
      af[mi] = *(const v8s*)&At[wm * 64 + mi * 16 + lo4][hi2 * 8];
#pragma unroll
    for (int ni = 0; ni < 4; ++ni)
      bf[ni] = *(const v8s*)&Bt[wn * 64 + ni * 16 + lo4][hi2 * 8];
#pragma unroll
    for (int mi = 0; mi < 4; ++mi)
#pragma unroll
      for (int ni = 0; ni < 4; ++ni)
        acc[mi][ni] = mfma_bf16(af[mi], bf[ni], acc[mi][ni]);
    __syncthreads();
  }
#pragma unroll
  for (int mi = 0; mi < 4; ++mi)
#pragma unroll
    for (int ni = 0; ni < 4; ++ni)
#pragma unroll
      for (int r = 0; r < 4; ++r) {
        int row = row0 + wm * 64 + mi * 16 + hi2 * 4 + r;
        int col = col0 + wn * 64 + ni * 16 + lo4;
        fcout[(size_t)row * DM + col] =
            acc[mi][ni][r] + fcb[col] + resid[(size_t)row * DM + col];
      }
}

// ---------- row LayerNorm: out = LN(x) * g + b ----------
__global__ __launch_bounds__(256) void ln_rows(
    const float* __restrict__ x, const float* __restrict__ lng,
    const float* __restrict__ lnb, float* __restrict__ out) {
  const int row = blockIdx.x * 4 + (threadIdx.x >> 6);
  const int l = threadIdx.x & 63;
  const float* xr = x + (size_t)row * DM;
  float4 v[4];
  float s = 0.f, q2 = 0.f;
#pragma unroll
  for (int j = 0; j < 4; ++j) {
    v[j] = *reinterpret_cast<const float4*>(xr + l * 4 + j * 256);
    s += v[j].x + v[j].y + v[j].z + v[j].w;
    q2 += v[j].x * v[j].x + v[j].y * v[j].y + v[j].z * v[j].z + v[j].w * v[j].w;
  }
#pragma unroll
  for (int d = 1; d < 64; d <<= 1) {
    s += __shfl_xor(s, d);
    q2 += __shfl_xor(q2, d);
  }
  const float mean = s * (1.f / DM);
  const float var = q2 * (1.f / DM) - mean * mean;
  const float rstd = rsqrtf(var + 1e-5f);
#pragma unroll
  for (int j = 0; j < 4; ++j) {
    int c = l * 4 + j * 256;
    float4 g = *reinterpret_cast<const float4*>(lng + c);
    float4 b = *reinterpret_cast<const float4*>(lnb + c);
    float4 y;
    y.x = (v[j].x - mean) * rstd * g.x + b.x;
    y.y = (v[j].y - mean) * rstd * g.y + b.y;
    y.z = (v[j].z - mean) * rstd * g.z + b.z;
    y.w = (v[j].w - mean) * rstd * g.w + b.w;
    *reinterpret_cast<float4*>(out + (size_t)row * DM + c) = y;
  }
}

extern "C" void kernel_launch(void* const* d_in, const int* in_sizes, int n_in,
                              void* d_out, int out_size, void* d_ws, size_t ws_size,
                              hipStream_t stream) {
  const float* q = (const float*)d_in[0];
  const float* k = (const float*)d_in[1];
  const float* v = (const float*)d_in[2];
  const int* seq_len = (const int*)d_in[3];
  const float* w_qs = (const float*)d_in[4];
  const float* b_qs = (const float*)d_in[5];
  const float* w_ks = (const float*)d_in[6];
  const float* b_ks = (const float*)d_in[7];
  const float* w_vs = (const float*)d_in[8];
  const float* b_vs = (const float*)d_in[9];
  const float* fcw = (const float*)d_in[10];
  const float* fcb = (const float*)d_in[11];
  const float* lng = (const float*)d_in[12];
  const float* lnb = (const float*)d_in[13];

  float* out0 = (float*)d_out;
  float* attn_out = out0 + (size_t)NB * SL * DM;

  const size_t PLANE = (size_t)NB * SL * DM;   // 4M elems
  const size_t WSZ = (size_t)DM * DM;          // 1M elems
  u16* wsu = (u16*)d_ws;
  u16* qh = wsu;              // bf16 planes during proj/attn phase
  u16* kh = wsu + PLANE;
  u16* vt = wsu + 2 * PLANE;
  float* ctx = out0;

  // scratch in the not-yet-written attn f32 region
  u16* satt = (u16*)attn_out;
  u16* qxh = satt;
  u16* qxl = satt + PLANE;
  u16* kxh = satt + 2 * PLANE;
  u16* kxl = satt + 3 * PLANE;
  u16* vxh = satt + 4 * PLANE;
  u16* wqb = satt + 5 * PLANE;
  u16* wkb = satt + 5 * PLANE + WSZ;
  u16* wvb = satt + 5 * PLANE + 2 * WSZ;

  // post-attn reuse of ws: fcout f32 (16MB) + fcwb (2MB)
  float* fcout = (float*)d_ws;
  u16* fcwb = wsu + 4 * PLANE;   // bytes [16MB,18MB)

  cvt_qkv<<<3072, 256, 0, stream>>>(q, k, v, qxh, qxl, kxh, kxl, vxh);
  cvt_w3<<<768, 256, 0, stream>>>(w_qs, w_ks, w_vs, wqb, wkb, wvb);
  gemm_proj<<<768, 256, 0, stream>>>(qxh, qxl, kxh, kxl, vxh, wqb, wkb, wvb,
                                     b_qs, b_ks, b_vs, qh, kh, vt);
  attn_kernel<<<dim3(64, 64), 256, 0, stream>>>(qh, kh, vt, seq_len, attn_out, ctx);
  cvt_hi_k<<<512, 256, 0, stream>>>(fcw, fcwb, (int)WSZ);
  gemm_fc<<<256, 256, 0, stream>>>(ctx, fcwb, fcb, q, fcout);
  ln_rows<<<1024, 256, 0, stream>>>(fcout, lng, lnb, out0);
}

// Round 26
// 276.674 us; speedup vs baseline: 2.7007x; 1.0140x over previous
//
#include <hip/hip_runtime.h>
#include <math.h>

#define NB 4
#define SL 1024
#define DM 1024
#define NH 16
#define HD 64

typedef short v8s __attribute__((ext_vector_type(8)));
typedef float v4f __attribute__((ext_vector_type(4)));
typedef float v8f __attribute__((ext_vector_type(8)));
typedef unsigned short u16;
typedef unsigned int u32;

__device__ __forceinline__ v4f mfma_bf16(v8s a, v8s b, v4f c) {
  return __builtin_amdgcn_mfma_f32_16x16x32_bf16(a, b, c, 0, 0, 0);
}
__device__ __forceinline__ float bf2f(u16 x) {
  union { unsigned int u; float f; } cv; cv.u = ((unsigned int)x) << 16; return cv.f;
}
__device__ __forceinline__ u16 f2bf(float f) {
  union { float f; unsigned int u; } cv; cv.f = f;
  unsigned int r = cv.u + 0x7FFFu + ((cv.u >> 16) & 1u);
  return (u16)(r >> 16);
}
__device__ __forceinline__ v8s cvt8h(const float* p) {
  v8f x = *reinterpret_cast<const v8f*>(p);
  v8s h;
#pragma unroll
  for (int j = 0; j < 8; ++j) h[j] = (short)f2bf(x[j]);
  return h;
}
// async global->LDS: per-lane global src, WAVE-UNIFORM lds base; HW writes
// lane l at base + l*16B (guide m104). 16B per lane.
__device__ __forceinline__ void gl16(const u16* g, u16* lds_base_uniform) {
  __builtin_amdgcn_global_load_lds(
      (const __attribute__((address_space(1))) u32*)g,
      (__attribute__((address_space(3))) u32*)lds_base_uniform, 16, 0, 0);
}

// ---------- merged pre-convert: q,k (hi/lo) + v (hi) ----------
__global__ __launch_bounds__(256) void cvt_qkv(
    const float* __restrict__ q, const float* __restrict__ k,
    const float* __restrict__ v, u16* __restrict__ qxh, u16* __restrict__ qxl,
    u16* __restrict__ kxh, u16* __restrict__ kxl, u16* __restrict__ vxh) {
  const unsigned total = 3u << 20;
  for (unsigned g = blockIdx.x * 256 + threadIdx.x; g < total;
       g += gridDim.x * 256) {
    unsigned r = g >> 20, local = g & ((1u << 20) - 1), i = local * 4;
    const float* src = (r == 0) ? q : (r == 1) ? k : v;
    float4 x = *reinterpret_cast<const float4*>(src + i);
    ushort4 h;
    h.x = f2bf(x.x); h.y = f2bf(x.y); h.z = f2bf(x.z); h.w = f2bf(x.w);
    if (r == 0) {
      ushort4 l;
      l.x = f2bf(x.x - bf2f(h.x)); l.y = f2bf(x.y - bf2f(h.y));
      l.z = f2bf(x.z - bf2f(h.z)); l.w = f2bf(x.w - bf2f(h.w));
      *reinterpret_cast<ushort4*>(qxh + i) = h;
      *reinterpret_cast<ushort4*>(qxl + i) = l;
    } else if (r == 1) {
      ushort4 l;
      l.x = f2bf(x.x - bf2f(h.x)); l.y = f2bf(x.y - bf2f(h.y));
      l.z = f2bf(x.z - bf2f(h.z)); l.w = f2bf(x.w - bf2f(h.w));
      *reinterpret_cast<ushort4*>(kxh + i) = h;
      *reinterpret_cast<ushort4*>(kxl + i) = l;
    } else {
      *reinterpret_cast<ushort4*>(vxh + i) = h;
    }
  }
}
// merged weight convert: w_qs,w_ks,w_vs,fc_w -> bf16
__global__ __launch_bounds__(256) void cvt_w4(
    const float* __restrict__ wq, const float* __restrict__ wk,
    const float* __restrict__ wv, const float* __restrict__ fw,
    u16* __restrict__ wqb, u16* __restrict__ wkb, u16* __restrict__ wvb,
    u16* __restrict__ fwb) {
  const unsigned total = 4u << 18;
  for (unsigned g = blockIdx.x * 256 + threadIdx.x; g < total;
       g += gridDim.x * 256) {
    unsigned r = g >> 18, local = g & ((1u << 18) - 1), i = local * 4;
    const float* src = (r == 0) ? wq : (r == 1) ? wk : (r == 2) ? wv : fw;
    u16* dst = (r == 0) ? wqb : (r == 1) ? wkb : (r == 2) ? wvb : fwb;
    float4 x = *reinterpret_cast<const float4*>(src + i);
    ushort4 h;
    h.x = f2bf(x.x); h.y = f2bf(x.y); h.z = f2bf(x.z); h.w = f2bf(x.w);
    *reinterpret_cast<ushort4*>(dst + i) = h;
  }
}

// ---------- m97-style LDS-tiled projection GEMM (global_load_lds) ----------
__global__ __launch_bounds__(256) void gemm_proj(
    const u16* __restrict__ qxh, const u16* __restrict__ qxl,
    const u16* __restrict__ kxh, const u16* __restrict__ kxl,
    const u16* __restrict__ vxh, const u16* __restrict__ wqb,
    const u16* __restrict__ wkb, const u16* __restrict__ wvb,
    const float* __restrict__ b_qs, const float* __restrict__ b_ks,
    const float* __restrict__ b_vs, u16* __restrict__ qh,
    u16* __restrict__ kh, u16* __restrict__ vt) {
  __shared__ u16 Ah[128 * 32];
  __shared__ u16 Al[128 * 32];
  __shared__ u16 Bs[128 * 32];
  const int bid = blockIdx.x;
  const int sel = bid >> 8;                // 0=q,1=k,2=v
  const int tb = bid & 255;
  const int row0 = (tb >> 3) * 128;
  const int col0 = (tb & 7) * 128;
  const u16* Xh = (sel == 0) ? qxh : (sel == 1) ? kxh : vxh;
  const u16* Xl = (sel == 1) ? kxl : qxl;
  const u16* Wb = (sel == 0) ? wqb : (sel == 1) ? wkb : wvb;
  const bool two = (sel < 2);

  const int tid = threadIdx.x;
  const int wid = tid >> 6, l = tid & 63, lo4 = l & 15, hi2 = l >> 4;
  const int wm = wid >> 1, wn = wid & 1;

  // staging: chunk c (c = i*256+tid) covers LDS u16 [c*8, c*8+8), i.e. the
  // tile element (row c>>2, col (c&3)*8). Wave-uniform LDS base per gl16.
  const int r0s = tid >> 2, c0s = (tid & 3) * 8;            // chunk i=0
  const int r1s = (tid + 256) >> 2, c1s = (tid & 3) * 8;    // chunk i=1
  const int ub0 = (wid * 64) * 8;          // uniform base, chunk 0
  const int ub1 = (256 + wid * 64) * 8;    // uniform base, chunk 1

  v4f acc[4][4];
#pragma unroll
  for (int i = 0; i < 4; ++i)
#pragma unroll
    for (int j = 0; j < 4; ++j) acc[i][j] = (v4f){0.f, 0.f, 0.f, 0.f};

  for (int ks = 0; ks < 32; ++ks) {
    const int k0 = ks * 32;
    gl16(Xh + (size_t)(row0 + r0s) * DM + k0 + c0s, Ah + ub0);
    gl16(Xh + (size_t)(row0 + r1s) * DM + k0 + c1s, Ah + ub1);
    if (two) {
      gl16(Xl + (size_t)(row0 + r0s) * DM + k0 + c0s, Al + ub0);
      gl16(Xl + (size_t)(row0 + r1s) * DM + k0 + c1s, Al + ub1);
    }
    gl16(Wb + (size_t)(col0 + r0s) * DM + k0 + c0s, Bs + ub0);
    gl16(Wb + (size_t)(col0 + r1s) * DM + k0 + c1s, Bs + ub1);
    __syncthreads();
    v8s af[4], alf[4], bf[4];
#pragma unroll
    for (int mi = 0; mi < 4; ++mi)
      af[mi] = *(const v8s*)&Ah[(wm * 64 + mi * 16 + lo4) * 32 + hi2 * 8];
#pragma unroll
    for (int ni = 0; ni < 4; ++ni)
      bf[ni] = *(const v8s*)&Bs[(wn * 64 + ni * 16 + lo4) * 32 + hi2 * 8];
    if (two) {
#pragma unroll
      for (int mi = 0; mi < 4; ++mi)
        alf[mi] = *(const v8s*)&Al[(wm * 64 + mi * 16 + lo4) * 32 + hi2 * 8];
    }
#pragma unroll
    for (int mi = 0; mi < 4; ++mi)
#pragma unroll
      for (int ni = 0; ni < 4; ++ni) {
        acc[mi][ni] = mfma_bf16(af[mi], bf[ni], acc[mi][ni]);
        if (two) acc[mi][ni] = mfma_bf16(alf[mi], bf[ni], acc[mi][ni]);
      }
    __syncthreads();
  }

  const float* bias = (sel == 0) ? b_qs : (sel == 1) ? b_ks : b_vs;
#pragma unroll
  for (int mi = 0; mi < 4; ++mi)
#pragma unroll
    for (int ni = 0; ni < 4; ++ni)
#pragma unroll
      for (int r = 0; r < 4; ++r) {
        int row = row0 + wm * 64 + mi * 16 + hi2 * 4 + r;
        int col = col0 + wn * 64 + ni * 16 + lo4;
        float vv = acc[mi][ni][r] + bias[col];
        int b_ = row >> 10, pos = row & (SL - 1);
        int h = col >> 6, d = col & (HD - 1);
        if (sel < 2) {
          u16* out = sel ? kh : qh;
          out[((size_t)(b_ * NH + h) * SL + pos) * HD + d] = f2bf(vv);
        } else {
          vt[((size_t)(b_ * NH + h) * HD + d) * SL + pos] = f2bf(vv);
        }
      }
}

// ---------- attention (unchanged) ----------
__global__ __launch_bounds__(256) void attn_kernel(
    const u16* __restrict__ qh, const u16* __restrict__ kh,
    const u16* __restrict__ vt, const int* __restrict__ seq_len,
    float* __restrict__ attn_out, float* __restrict__ ctx) {
  const int bh = blockIdx.x;
  const int qt = blockIdx.y;
  const int b_ = bh >> 4, h = bh & 15;
  const int seqb = seq_len[b_];
  const int tid = threadIdx.x;
  const int wv = tid >> 6, l = tid & 63;
  const int lo4 = l & 15, hi2 = l >> 4;

  __shared__ u16 p_lds[16][1032];
  __shared__ float red_m[4][16];
  __shared__ float red_s[4][16];

  const u16* qp = qh + ((size_t)bh * SL + qt * 16 + lo4) * HD + hi2 * 8;
  v8s aq0 = *(const v8s*)(qp);
  v8s aq1 = *(const v8s*)(qp + 32);

  const int kbase = wv * 256;
  const u16* Kb = kh + (size_t)bh * SL * HD;

  v4f s[16];
#pragma unroll
  for (int kt = 0; kt < 16; ++kt) {
    int key = kbase + kt * 16 + lo4;
    const u16* kp = Kb + key * HD + hi2 * 8;
    v8s bk0 = *(const v8s*)kp;
    v8s bk1 = *(const v8s*)(kp + 32);
    v4f acc = (v4f){0.f, 0.f, 0.f, 0.f};
    acc = mfma_bf16(aq0, bk0, acc);
    acc = mfma_bf16(aq1, bk1, acc);
    bool km = key >= seqb;
#pragma unroll
    for (int r = 0; r < 4; ++r)
      s[kt][r] = km ? -INFINITY : acc[r] * 0.125f;
  }

  float m[4];
#pragma unroll
  for (int r = 0; r < 4; ++r) {
    float mm = s[0][r];
#pragma unroll
    for (int kt = 1; kt < 16; ++kt) mm = fmaxf(mm, s[kt][r]);
    for (int d2 = 1; d2 < 16; d2 <<= 1) mm = fmaxf(mm, __shfl_xor(mm, d2));
    m[r] = mm;
  }
  if (lo4 == 0) {
#pragma unroll
    for (int r = 0; r < 4; ++r) red_m[wv][hi2 * 4 + r] = m[r];
  }
  __syncthreads();
#pragma unroll
  for (int r = 0; r < 4; ++r) {
    float mm = red_m[0][hi2 * 4 + r];
    mm = fmaxf(mm, red_m[1][hi2 * 4 + r]);
    mm = fmaxf(mm, red_m[2][hi2 * 4 + r]);
    mm = fmaxf(mm, red_m[3][hi2 * 4 + r]);
    m[r] = mm;
  }
  float sm[4] = {0.f, 0.f, 0.f, 0.f};
#pragma unroll
  for (int kt = 0; kt < 16; ++kt) {
#pragma unroll
    for (int r = 0; r < 4; ++r) {
      float p = expf(s[kt][r] - m[r]);
      s[kt][r] = p;
      sm[r] += p;
    }
  }
#pragma unroll
  for (int r = 0; r < 4; ++r)
    for (int d2 = 1; d2 < 16; d2 <<= 1) sm[r] += __shfl_xor(sm[r], d2);
  if (lo4 == 0) {
#pragma unroll
    for (int r = 0; r < 4; ++r) red_s[wv][hi2 * 4 + r] = sm[r];
  }
  __syncthreads();
  float inv[4];
#pragma unroll
  for (int r = 0; r < 4; ++r) {
    float t = red_s[0][hi2 * 4 + r] + red_s[1][hi2 * 4 + r] +
              red_s[2][hi2 * 4 + r] + red_s[3][hi2 * 4 + r];
    inv[r] = 1.f / t;
  }
#pragma unroll
  for (int r = 0; r < 4; ++r) {
    int row = hi2 * 4 + r;
    bool qm = (qt * 16 + row) >= seqb;
    float sc = qm ? 0.f : inv[r];
#pragma unroll
    for (int kt = 0; kt < 16; ++kt) {
      int key = kbase + kt * 16 + lo4;
      p_lds[row][key] = f2bf(s[kt][r] * sc);
    }
  }
  __syncthreads();
  float* aout = attn_out + ((size_t)(h * NB + b_) * SL + qt * 16) * SL;
#pragma unroll
  for (int i = 0; i < 16; ++i) {
    int idx = (tid + i * 256) * 4;
    int row = idx >> 10, key = idx & 1023;
    ushort4 pv = *(const ushort4*)&p_lds[row][key];
    float4 o4 = make_float4(bf2f(pv.x), bf2f(pv.y), bf2f(pv.z), bf2f(pv.w));
    *reinterpret_cast<float4*>(&aout[(size_t)row * SL + key]) = o4;
  }
  v4f o = (v4f){0.f, 0.f, 0.f, 0.f};
  const u16* vbase = vt + (size_t)bh * HD * SL + (wv * 16 + lo4) * SL + hi2 * 8;
#pragma unroll 8
  for (int c = 0; c < 32; ++c) {
    v8s pa = *(const v8s*)&p_lds[lo4][c * 32 + hi2 * 8];
    v8s vb = *(const v8s*)(vbase + c * 32);
    o = mfma_bf16(pa, vb, o);
  }
#pragma unroll
  for (int r = 0; r < 4; ++r) {
    int row = qt * 16 + hi2 * 4 + r;
    ctx[((size_t)b_ * SL + row) * DM + h * HD + wv * 16 + lo4] = o[r];
  }
}

// ---------- fc GEMM: fcout = ctx @ fcw^T + fcb + residual ----------
__global__ __launch_bounds__(256) void gemm_fc(
    const float* __restrict__ ctx, const u16* __restrict__ fcwb,
    const float* __restrict__ fcb, const float* __restrict__ resid,
    float* __restrict__ fcout) {
  __shared__ u16 As[128 * 32];
  __shared__ u16 Bs[128 * 32];
  const int row0 = (blockIdx.x >> 3) * 128;
  const int col0 = (blockIdx.x & 7) * 128;
  const int tid = threadIdx.x;
  const int wid = tid >> 6, l = tid & 63, lo4 = l & 15, hi2 = l >> 4;
  const int wm = wid >> 1, wn = wid & 1;
  const int r0s = tid >> 2, c0s = (tid & 3) * 8;
  const int r1s = (tid + 256) >> 2;
  const int ub0 = (wid * 64) * 8;
  const int ub1 = (256 + wid * 64) * 8;

  v4f acc[4][4];
#pragma unroll
  for (int i = 0; i < 4; ++i)
#pragma unroll
    for (int j = 0; j < 4; ++j) acc[i][j] = (v4f){0.f, 0.f, 0.f, 0.f};

  for (int ks = 0; ks < 32; ++ks) {
    const int k0 = ks * 32;
    gl16(fcwb + (size_t)(col0 + r0s) * DM + k0 + c0s, Bs + ub0);
    gl16(fcwb + (size_t)(col0 + r1s) * DM + k0 + c0s, Bs + ub1);
    *(v8s*)&As[tid * 8] = cvt8h(ctx + (size_t)(row0 + r0s) * DM + k0 + c0s);
    *(v8s*)&As[(tid + 256) * 8] =
        cvt8h(ctx + (size_t)(row0 + r1s) * DM + k0 + c0s);
    __syncthreads();
    v8s af[4], bf[4];
#pragma unroll
    for (int mi = 0; mi < 4; ++mi)
      af[mi] = *(const v8s*)&As[(wm * 64 + mi * 16 + lo4) * 32 + hi2 * 8];
#pragma unroll
    for (int ni = 0; ni < 4; ++ni)
      bf[ni] = *(const v8s*)&Bs[(wn * 64 + ni * 16 + lo4) * 32 + hi2 * 8];
#pragma unroll
    for (int mi = 0; mi < 4; ++mi)
#pragma unroll
      for (int ni = 0; ni < 4; ++ni)
        acc[mi][ni] = mfma_bf16(af[mi], bf[ni], acc[mi][ni]);
    __syncthreads();
  }
#pragma unroll
  for (int mi = 0; mi < 4; ++mi)
#pragma unroll
    for (int ni = 0; ni < 4; ++ni)
#pragma unroll
      for (int r = 0; r < 4; ++r) {
        int row = row0 + wm * 64 + mi * 16 + hi2 * 4 + r;
        int col = col0 + wn * 64 + ni * 16 + lo4;
        fcout[(size_t)row * DM + col] =
            acc[mi][ni][r] + fcb[col] + resid[(size_t)row * DM + col];
      }
}

// ---------- row LayerNorm ----------
__global__ __launch_bounds__(256) void ln_rows(
    const float* __restrict__ x, const float* __restrict__ lng,
    const float* __restrict__ lnb, float* __restrict__ out) {
  const int row = blockIdx.x * 4 + (threadIdx.x >> 6);
  const int l = threadIdx.x & 63;
  const float* xr = x + (size_t)row * DM;
  float4 v[4];
  float s = 0.f, q2 = 0.f;
#pragma unroll
  for (int j = 0; j < 4; ++j) {
    v[j] = *reinterpret_cast<const float4*>(xr + l * 4 + j * 256);
    s += v[j].x + v[j].y + v[j].z + v[j].w;
    q2 += v[j].x * v[j].x + v[j].y * v[j].y + v[j].z * v[j].z + v[j].w * v[j].w;
  }
#pragma unroll
  for (int d = 1; d < 64; d <<= 1) {
    s += __shfl_xor(s, d);
    q2 += __shfl_xor(q2, d);
  }
  const float mean = s * (1.f / DM);
  const float var = q2 * (1.f / DM) - mean * mean;
  const float rstd = rsqrtf(var + 1e-5f);
#pragma unroll
  for (int j = 0; j < 4; ++j) {
    int c = l * 4 + j * 256;
    float4 g = *reinterpret_cast<const float4*>(lng + c);
    float4 b = *reinterpret_cast<const float4*>(lnb + c);
    float4 y;
    y.x = (v[j].x - mean) * rstd * g.x + b.x;
    y.y = (v[j].y - mean) * rstd * g.y + b.y;
    y.z = (v[j].z - mean) * rstd * g.z + b.z;
    y.w = (v[j].w - mean) * rstd * g.w + b.w;
    *reinterpret_cast<float4*>(out + (size_t)row * DM + c) = y;
  }
}

extern "C" void kernel_launch(void* const* d_in, const int* in_sizes, int n_in,
                              void* d_out, int out_size, void* d_ws, size_t ws_size,
                              hipStream_t stream) {
  const float* q = (const float*)d_in[0];
  const float* k = (const float*)d_in[1];
  const float* v = (const float*)d_in[2];
  const int* seq_len = (const int*)d_in[3];
  const float* w_qs = (const float*)d_in[4];
  const float* b_qs = (const float*)d_in[5];
  const float* w_ks = (const float*)d_in[6];
  const float* b_ks = (const float*)d_in[7];
  const float* w_vs = (const float*)d_in[8];
  const float* b_vs = (const float*)d_in[9];
  const float* fcw = (const float*)d_in[10];
  const float* fcb = (const float*)d_in[11];
  const float* lng = (const float*)d_in[12];
  const float* lnb = (const float*)d_in[13];

  float* out0 = (float*)d_out;
  float* attn_out = out0 + (size_t)NB * SL * DM;

  const size_t PLANE = (size_t)NB * SL * DM;   // 4M elems
  const size_t WSZ = (size_t)DM * DM;          // 1M elems
  u16* wsu = (u16*)d_ws;
  u16* qh = wsu;
  u16* kh = wsu + PLANE;
  u16* vt = wsu + 2 * PLANE;
  u16* fcwb = wsu + 3 * PLANE;   // ws bytes [24,26MB) — r24 proved ws>=34MB
  float* ctx = out0;

  // scratch in the not-yet-written attn f32 region
  u16* satt = (u16*)attn_out;
  u16* qxh = satt;
  u16* qxl = satt + PLANE;
  u16* kxh = satt + 2 * PLANE;
  u16* kxl = satt + 3 * PLANE;
  u16* vxh = satt + 4 * PLANE;
  u16* wqb = satt + 5 * PLANE;
  u16* wkb = satt + 5 * PLANE + WSZ;
  u16* wvb = satt + 5 * PLANE + 2 * WSZ;

  float* fcout = (float*)d_ws;   // [0,16MB) — qh/kh dead post-attn

  cvt_qkv<<<3072, 256, 0, stream>>>(q, k, v, qxh, qxl, kxh, kxl, vxh);
  cvt_w4<<<1024, 256, 0, stream>>>(w_qs, w_ks, w_vs, fcw, wqb, wkb, wvb, fcwb);
  gemm_proj<<<768, 256, 0, stream>>>(qxh, qxl, kxh, kxl, vxh, wqb, wkb, wvb,
                                     b_qs, b_ks, b_vs, qh, kh, vt);
  attn_kernel<<<dim3(64, 64), 256, 0, stream>>>(qh, kh, vt, seq_len, attn_out, ctx);
  gemm_fc<<<256, 256, 0, stream>>>(ctx, fcwb, fcb, q, fcout);
  ln_rows<<<1024, 256, 0, stream>>>(fcout, lng, lnb, out0);
}

// Round 27
// 183.221 us; speedup vs baseline: 4.0782x; 1.5101x over previous
//
#include <hip/hip_runtime.h>
#include <math.h>

#define NB 4
#define SL 1024
#define DM 1024
#define NH 16
#define HD 64

typedef short v8s __attribute__((ext_vector_type(8)));
typedef float v4f __attribute__((ext_vector_type(4)));
typedef float v8f __attribute__((ext_vector_type(8)));
typedef unsigned short u16;
typedef unsigned int u32;

__device__ __forceinline__ v4f mfma_bf16(v8s a, v8s b, v4f c) {
  return __builtin_amdgcn_mfma_f32_16x16x32_bf16(a, b, c, 0, 0, 0);
}
__device__ __forceinline__ float bf2f(u16 x) {
  union { unsigned int u; float f; } cv; cv.u = ((unsigned int)x) << 16; return cv.f;
}
__device__ __forceinline__ u16 f2bf(float f) {
  union { float f; unsigned int u; } cv; cv.f = f;
  unsigned int r = cv.u + 0x7FFFu + ((cv.u >> 16) & 1u);
  return (u16)(r >> 16);
}
__device__ __forceinline__ v8s cvt8h(const float* p) {
  v8f x = *reinterpret_cast<const v8f*>(p);
  v8s h;
#pragma unroll
  for (int j = 0; j < 8; ++j) h[j] = (short)f2bf(x[j]);
  return h;
}
// async global->LDS: per-lane global src, wave-uniform lds base (m104).
__device__ __forceinline__ void gl16(const u16* g, u16* lds_base_uniform) {
  __builtin_amdgcn_global_load_lds(
      (const __attribute__((address_space(1))) u32*)g,
      (__attribute__((address_space(3))) u32*)lds_base_uniform, 16, 0, 0);
}

// ---------- merged pre-convert: q,k,v -> single bf16 planes ----------
__global__ __launch_bounds__(256) void cvt_qkv(
    const float* __restrict__ q, const float* __restrict__ k,
    const float* __restrict__ v, u16* __restrict__ qxb,
    u16* __restrict__ kxb, u16* __restrict__ vxb) {
  const unsigned total = 3u << 20;  // 3M float4
  for (unsigned g = blockIdx.x * 256 + threadIdx.x; g < total;
       g += gridDim.x * 256) {
    unsigned r = g >> 20, local = g & ((1u << 20) - 1), i = local * 4;
    const float* src = (r == 0) ? q : (r == 1) ? k : v;
    u16* dst = (r == 0) ? qxb : (r == 1) ? kxb : vxb;
    float4 x = *reinterpret_cast<const float4*>(src + i);
    ushort4 h;
    h.x = f2bf(x.x); h.y = f2bf(x.y); h.z = f2bf(x.z); h.w = f2bf(x.w);
    *reinterpret_cast<ushort4*>(dst + i) = h;
  }
}
// merged weight convert: w_qs,w_ks,w_vs,fc_w -> bf16
__global__ __launch_bounds__(256) void cvt_w4(
    const float* __restrict__ wq, const float* __restrict__ wk,
    const float* __restrict__ wv, const float* __restrict__ fw,
    u16* __restrict__ wqb, u16* __restrict__ wkb, u16* __restrict__ wvb,
    u16* __restrict__ fwb) {
  const unsigned total = 4u << 18;
  for (unsigned g = blockIdx.x * 256 + threadIdx.x; g < total;
       g += gridDim.x * 256) {
    unsigned r = g >> 18, local = g & ((1u << 18) - 1), i = local * 4;
    const float* src = (r == 0) ? wq : (r == 1) ? wk : (r == 2) ? wv : fw;
    u16* dst = (r == 0) ? wqb : (r == 1) ? wkb : (r == 2) ? wvb : fwb;
    float4 x = *reinterpret_cast<const float4*>(src + i);
    ushort4 h;
    h.x = f2bf(x.x); h.y = f2bf(x.y); h.z = f2bf(x.z); h.w = f2bf(x.w);
    *reinterpret_cast<ushort4*>(dst + i) = h;
  }
}

// ---------- m97-shape 1-term projection GEMM ----------
__global__ __launch_bounds__(256) void gemm_proj(
    const u16* __restrict__ qxb, const u16* __restrict__ kxb,
    const u16* __restrict__ vxb, const u16* __restrict__ wqb,
    const u16* __restrict__ wkb, const u16* __restrict__ wvb,
    const float* __restrict__ b_qs, const float* __restrict__ b_ks,
    const float* __restrict__ b_vs, u16* __restrict__ qh,
    u16* __restrict__ kh, u16* __restrict__ vt) {
  __shared__ u16 As[128 * 32];
  __shared__ u16 Bs[128 * 32];
  const int bid = blockIdx.x;
  const int sel = bid >> 8;                // 0=q,1=k,2=v
  const int tb = bid & 255;
  const int row0 = (tb >> 3) * 128;
  const int col0 = (tb & 7) * 128;
  const u16* Xb = (sel == 0) ? qxb : (sel == 1) ? kxb : vxb;
  const u16* Wb = (sel == 0) ? wqb : (sel == 1) ? wkb : wvb;

  const int tid = threadIdx.x;
  const int wid = tid >> 6, l = tid & 63, lo4 = l & 15, hi2 = l >> 4;
  const int wm = wid >> 1, wn = wid & 1;

  const int r0s = tid >> 2, c0s = (tid & 3) * 8;
  const int r1s = (tid + 256) >> 2;
  const int ub0 = (wid * 64) * 8;
  const int ub1 = (256 + wid * 64) * 8;

  v4f acc[4][4];
#pragma unroll
  for (int i = 0; i < 4; ++i)
#pragma unroll
    for (int j = 0; j < 4; ++j) acc[i][j] = (v4f){0.f, 0.f, 0.f, 0.f};

  for (int ks = 0; ks < 32; ++ks) {
    const int k0 = ks * 32;
    gl16(Xb + (size_t)(row0 + r0s) * DM + k0 + c0s, As + ub0);
    gl16(Xb + (size_t)(row0 + r1s) * DM + k0 + c0s, As + ub1);
    gl16(Wb + (size_t)(col0 + r0s) * DM + k0 + c0s, Bs + ub0);
    gl16(Wb + (size_t)(col0 + r1s) * DM + k0 + c0s, Bs + ub1);
    __syncthreads();
    v8s af[4], bf[4];
#pragma unroll
    for (int mi = 0; mi < 4; ++mi)
      af[mi] = *(const v8s*)&As[(wm * 64 + mi * 16 + lo4) * 32 + hi2 * 8];
#pragma unroll
    for (int ni = 0; ni < 4; ++ni)
      bf[ni] = *(const v8s*)&Bs[(wn * 64 + ni * 16 + lo4) * 32 + hi2 * 8];
#pragma unroll
    for (int mi = 0; mi < 4; ++mi)
#pragma unroll
      for (int ni = 0; ni < 4; ++ni)
        acc[mi][ni] = mfma_bf16(af[mi], bf[ni], acc[mi][ni]);
    __syncthreads();
  }

  const float* bias = (sel == 0) ? b_qs : (sel == 1) ? b_ks : b_vs;
#pragma unroll
  for (int mi = 0; mi < 4; ++mi)
#pragma unroll
    for (int ni = 0; ni < 4; ++ni)
#pragma unroll
      for (int r = 0; r < 4; ++r) {
        int row = row0 + wm * 64 + mi * 16 + hi2 * 4 + r;
        int col = col0 + wn * 64 + ni * 16 + lo4;
        float vv = acc[mi][ni][r] + bias[col];
        int b_ = row >> 10, pos = row & (SL - 1);
        int h = col >> 6, d = col & (HD - 1);
        if (sel < 2) {
          u16* out = sel ? kh : qh;
          out[((size_t)(b_ * NH + h) * SL + pos) * HD + d] = f2bf(vv);
        } else {
          vt[((size_t)(b_ * NH + h) * HD + d) * SL + pos] = f2bf(vv);
        }
      }
}

// ---------- attention with mask-aware compute skip ----------
__global__ __launch_bounds__(256) void attn_kernel(
    const u16* __restrict__ qh, const u16* __restrict__ kh,
    const u16* __restrict__ vt, const int* __restrict__ seq_len,
    float* __restrict__ attn_out, float* __restrict__ ctx) {
  const int bh = blockIdx.x;
  const int qt = blockIdx.y;
  const int b_ = bh >> 4, h = bh & 15;
  const int seqb = seq_len[b_];
  const int tid = threadIdx.x;

  float* aout = attn_out + ((size_t)(h * NB + b_) * SL + qt * 16) * SL;

  // fully-masked q-tile: stream zeros (P 64KB + ctx 4KB), skip all compute
  if (qt * 16 >= seqb) {
    const float4 z = make_float4(0.f, 0.f, 0.f, 0.f);
#pragma unroll
    for (int i = 0; i < 16; ++i) {
      int idx = (tid + i * 256) * 4;
      int row = idx >> 10, key = idx & 1023;
      *reinterpret_cast<float4*>(&aout[(size_t)row * SL + key]) = z;
    }
    int r2 = tid >> 4, c2 = (tid & 15) * 4;
    *reinterpret_cast<float4*>(
        &ctx[((size_t)b_ * SL + qt * 16 + r2) * DM + h * HD + c2]) = z;
    return;
  }

  const int wv = tid >> 6, l = tid & 63;
  const int lo4 = l & 15, hi2 = l >> 4;

  __shared__ u16 p_lds[16][1032];
  __shared__ float red_m[4][16];
  __shared__ float red_s[4][16];

  const u16* qp = qh + ((size_t)bh * SL + qt * 16 + lo4) * HD + hi2 * 8;
  v8s aq0 = *(const v8s*)(qp);
  v8s aq1 = *(const v8s*)(qp + 32);

  const int kbase = wv * 256;
  const u16* Kb = kh + (size_t)bh * SL * HD;

  v4f s[16];
#pragma unroll
  for (int kt = 0; kt < 16; ++kt) {
    const bool kact = (kbase + kt * 16) < seqb;   // wave-uniform
    v4f acc = (v4f){0.f, 0.f, 0.f, 0.f};
    int key = kbase + kt * 16 + lo4;
    if (kact) {
      const u16* kp = Kb + key * HD + hi2 * 8;
      v8s bk0 = *(const v8s*)kp;
      v8s bk1 = *(const v8s*)(kp + 32);
      acc = mfma_bf16(aq0, bk0, acc);
      acc = mfma_bf16(aq1, bk1, acc);
    }
    bool km = key >= seqb;
#pragma unroll
    for (int r = 0; r < 4; ++r)
      s[kt][r] = km ? -INFINITY : acc[r] * 0.125f;
  }

  float m[4];
#pragma unroll
  for (int r = 0; r < 4; ++r) {
    float mm = s[0][r];
#pragma unroll
    for (int kt = 1; kt < 16; ++kt) mm = fmaxf(mm, s[kt][r]);
    for (int d2 = 1; d2 < 16; d2 <<= 1) mm = fmaxf(mm, __shfl_xor(mm, d2));
    m[r] = mm;
  }
  if (lo4 == 0) {
#pragma unroll
    for (int r = 0; r < 4; ++r) red_m[wv][hi2 * 4 + r] = m[r];
  }
  __syncthreads();
#pragma unroll
  for (int r = 0; r < 4; ++r) {
    float mm = red_m[0][hi2 * 4 + r];
    mm = fmaxf(mm, red_m[1][hi2 * 4 + r]);
    mm = fmaxf(mm, red_m[2][hi2 * 4 + r]);
    mm = fmaxf(mm, red_m[3][hi2 * 4 + r]);
    m[r] = mm;
  }
  float sm[4] = {0.f, 0.f, 0.f, 0.f};
#pragma unroll
  for (int kt = 0; kt < 16; ++kt) {
#pragma unroll
    for (int r = 0; r < 4; ++r) {
      float p = expf(s[kt][r] - m[r]);
      s[kt][r] = p;
      sm[r] += p;
    }
  }
#pragma unroll
  for (int r = 0; r < 4; ++r)
    for (int d2 = 1; d2 < 16; d2 <<= 1) sm[r] += __shfl_xor(sm[r], d2);
  if (lo4 == 0) {
#pragma unroll
    for (int r = 0; r < 4; ++r) red_s[wv][hi2 * 4 + r] = sm[r];
  }
  __syncthreads();
  float inv[4];
#pragma unroll
  for (int r = 0; r < 4; ++r) {
    float t = red_s[0][hi2 * 4 + r] + red_s[1][hi2 * 4 + r] +
              red_s[2][hi2 * 4 + r] + red_s[3][hi2 * 4 + r];
    inv[r] = 1.f / t;
  }
#pragma unroll
  for (int r = 0; r < 4; ++r) {
    int row = hi2 * 4 + r;
    bool qm = (qt * 16 + row) >= seqb;
    float sc = qm ? 0.f : inv[r];
#pragma unroll
    for (int kt = 0; kt < 16; ++kt) {
      int key = kbase + kt * 16 + lo4;
      p_lds[row][key] = f2bf(s[kt][r] * sc);
    }
  }
  __syncthreads();
#pragma unroll
  for (int i = 0; i < 16; ++i) {
    int idx = (tid + i * 256) * 4;
    int row = idx >> 10, key = idx & 1023;
    ushort4 pv = *(const ushort4*)&p_lds[row][key];
    float4 o4 = make_float4(bf2f(pv.x), bf2f(pv.y), bf2f(pv.z), bf2f(pv.w));
    *reinterpret_cast<float4*>(&aout[(size_t)row * SL + key]) = o4;
  }
  v4f o = (v4f){0.f, 0.f, 0.f, 0.f};
  const u16* vbase = vt + (size_t)bh * HD * SL + (wv * 16 + lo4) * SL + hi2 * 8;
#pragma unroll 8
  for (int c = 0; c < 32; ++c) {
    v8s pa = *(const v8s*)&p_lds[lo4][c * 32 + hi2 * 8];
    v8s vb = *(const v8s*)(vbase + c * 32);
    o = mfma_bf16(pa, vb, o);
  }
#pragma unroll
  for (int r = 0; r < 4; ++r) {
    int row = qt * 16 + hi2 * 4 + r;
    ctx[((size_t)b_ * SL + row) * DM + h * HD + wv * 16 + lo4] = o[r];
  }
}

// ---------- fc GEMM: fcout = ctx @ fcw^T + fcb + residual ----------
__global__ __launch_bounds__(256) void gemm_fc(
    const float* __restrict__ ctx, const u16* __restrict__ fcwb,
    const float* __restrict__ fcb, const float* __restrict__ resid,
    float* __restrict__ fcout) {
  __shared__ u16 As[128 * 32];
  __shared__ u16 Bs[128 * 32];
  const int row0 = (blockIdx.x >> 3) * 128;
  const int col0 = (blockIdx.x & 7) * 128;
  const int tid = threadIdx.x;
  const int wid = tid >> 6, l = tid & 63, lo4 = l & 15, hi2 = l >> 4;
  const int wm = wid >> 1, wn = wid & 1;
  const int r0s = tid >> 2, c0s = (tid & 3) * 8;
  const int r1s = (tid + 256) >> 2;
  const int ub0 = (wid * 64) * 8;
  const int ub1 = (256 + wid * 64) * 8;

  v4f acc[4][4];
#pragma unroll
  for (int i = 0; i < 4; ++i)
#pragma unroll
    for (int j = 0; j < 4; ++j) acc[i][j] = (v4f){0.f, 0.f, 0.f, 0.f};

  for (int ks = 0; ks < 32; ++ks) {
    const int k0 = ks * 32;
    gl16(fcwb + (size_t)(col0 + r0s) * DM + k0 + c0s, Bs + ub0);
    gl16(fcwb + (size_t)(col0 + r1s) * DM + k0 + c0s, Bs + ub1);
    *(v8s*)&As[tid * 8] = cvt8h(ctx + (size_t)(row0 + r0s) * DM + k0 + c0s);
    *(v8s*)&As[(tid + 256) * 8] =
        cvt8h(ctx + (size_t)(row0 + r1s) * DM + k0 + c0s);
    __syncthreads();
    v8s af[4], bf[4];
#pragma unroll
    for (int mi = 0; mi < 4; ++mi)
      af[mi] = *(const v8s*)&As[(wm * 64 + mi * 16 + lo4) * 32 + hi2 * 8];
#pragma unroll
    for (int ni = 0; ni < 4; ++ni)
      bf[ni] = *(const v8s*)&Bs[(wn * 64 + ni * 16 + lo4) * 32 + hi2 * 8];
#pragma unroll
    for (int mi = 0; mi < 4; ++mi)
#pragma unroll
      for (int ni = 0; ni < 4; ++ni)
        acc[mi][ni] = mfma_bf16(af[mi], bf[ni], acc[mi][ni]);
    __syncthreads();
  }
#pragma unroll
  for (int mi = 0; mi < 4; ++mi)
#pragma unroll
    for (int ni = 0; ni < 4; ++ni)
#pragma unroll
      for (int r = 0; r < 4; ++r) {
        int row = row0 + wm * 64 + mi * 16 + hi2 * 4 + r;
        int col = col0 + wn * 64 + ni * 16 + lo4;
        fcout[(size_t)row * DM + col] =
            acc[mi][ni][r] + fcb[col] + resid[(size_t)row * DM + col];
      }
}

// ---------- row LayerNorm ----------
__global__ __launch_bounds__(256) void ln_rows(
    const float* __restrict__ x, const float* __restrict__ lng,
    const float* __restrict__ lnb, float* __restrict__ out) {
  const int row = blockIdx.x * 4 + (threadIdx.x >> 6);
  const int l = threadIdx.x & 63;
  const float* xr = x + (size_t)row * DM;
  float4 v[4];
  float s = 0.f, q2 = 0.f;
#pragma unroll
  for (int j = 0; j < 4; ++j) {
    v[j] = *reinterpret_cast<const float4*>(xr + l * 4 + j * 256);
    s += v[j].x + v[j].y + v[j].z + v[j].w;
    q2 += v[j].x * v[j].x + v[j].y * v[j].y + v[j].z * v[j].z + v[j].w * v[j].w;
  }
#pragma unroll
  for (int d = 1; d < 64; d <<= 1) {
    s += __shfl_xor(s, d);
    q2 += __shfl_xor(q2, d);
  }
  const float mean = s * (1.f / DM);
  const float var = q2 * (1.f / DM) - mean * mean;
  const float rstd = rsqrtf(var + 1e-5f);
#pragma unroll
  for (int j = 0; j < 4; ++j) {
    int c = l * 4 + j * 256;
    float4 g = *reinterpret_cast<const float4*>(lng + c);
    float4 b = *reinterpret_cast<const float4*>(lnb + c);
    float4 y;
    y.x = (v[j].x - mean) * rstd * g.x + b.x;
    y.y = (v[j].y - mean) * rstd * g.y + b.y;
    y.z = (v[j].z - mean) * rstd * g.z + b.z;
    y.w = (v[j].w - mean) * rstd * g.w + b.w;
    *reinterpret_cast<float4*>(out + (size_t)row * DM + c) = y;
  }
}

extern "C" void kernel_launch(void* const* d_in, const int* in_sizes, int n_in,
                              void* d_out, int out_size, void* d_ws, size_t ws_size,
                              hipStream_t stream) {
  const float* q = (const float*)d_in[0];
  const float* k = (const float*)d_in[1];
  const float* v = (const float*)d_in[2];
  const int* seq_len = (const int*)d_in[3];
  const float* w_qs = (const float*)d_in[4];
  const float* b_qs = (const float*)d_in[5];
  const float* w_ks = (const float*)d_in[6];
  const float* b_ks = (const float*)d_in[7];
  const float* w_vs = (const float*)d_in[8];
  const float* b_vs = (const float*)d_in[9];
  const float* fcw = (const float*)d_in[10];
  const float* fcb = (const float*)d_in[11];
  const float* lng = (const float*)d_in[12];
  const float* lnb = (const float*)d_in[13];

  float* out0 = (float*)d_out;
  float* attn_out = out0 + (size_t)NB * SL * DM;

  const size_t PLANE = (size_t)NB * SL * DM;   // 4M elems
  const size_t WSZ = (size_t)DM * DM;          // 1M elems
  u16* wsu = (u16*)d_ws;
  u16* qh = wsu;
  u16* kh = wsu + PLANE;
  u16* vt = wsu + 2 * PLANE;
  u16* fcwb = wsu + 3 * PLANE;
  float* ctx = out0;

  // scratch in the not-yet-written attn f32 region
  u16* satt = (u16*)attn_out;
  u16* qxb = satt;
  u16* kxb = satt + PLANE;
  u16* vxb = satt + 2 * PLANE;
  u16* wqb = satt + 3 * PLANE;
  u16* wkb = satt + 3 * PLANE + WSZ;
  u16* wvb = satt + 3 * PLANE + 2 * WSZ;

  float* fcout = (float*)d_ws;   // [0,16MB) — qh/kh dead post-attn

  cvt_qkv<<<3072, 256, 0, stream>>>(q, k, v, qxb, kxb, vxb);
  cvt_w4<<<1024, 256, 0, stream>>>(w_qs, w_ks, w_vs, fcw, wqb, wkb, wvb, fcwb);
  gemm_proj<<<768, 256, 0, stream>>>(qxb, kxb, vxb, wqb, wkb, wvb,
                                     b_qs, b_ks, b_vs, qh, kh, vt);
  attn_kernel<<<dim3(64, 64), 256, 0, stream>>>(qh, kh, vt, seq_len, attn_out, ctx);
  gemm_fc<<<256, 256, 0, stream>>>(ctx, fcwb, fcb, q, fcout);
  ln_rows<<<1024, 256, 0, stream>>>(fcout, lng, lnb, out0);
}

// Round 28
// 170.351 us; speedup vs baseline: 4.3863x; 1.0755x over previous
//
#include <hip/hip_runtime.h>
#include <math.h>

#define NB 4
#define SL 1024
#define DM 1024
#define NH 16
#define HD 64

typedef short v8s __attribute__((ext_vector_type(8)));
typedef float v4f __attribute__((ext_vector_type(4)));
typedef float v8f __attribute__((ext_vector_type(8)));
typedef unsigned short u16;
typedef unsigned int u32;

__device__ __forceinline__ v4f mfma_bf16(v8s a, v8s b, v4f c) {
  return __builtin_amdgcn_mfma_f32_16x16x32_bf16(a, b, c, 0, 0, 0);
}
__device__ __forceinline__ float bf2f(u16 x) {
  union { unsigned int u; float f; } cv; cv.u = ((unsigned int)x) << 16; return cv.f;
}
__device__ __forceinline__ u16 f2bf(float f) {
  union { float f; unsigned int u; } cv; cv.f = f;
  unsigned int r = cv.u + 0x7FFFu + ((cv.u >> 16) & 1u);
  return (u16)(r >> 16);
}
__device__ __forceinline__ v8s cvt8h(const float* p) {
  v8f x = *reinterpret_cast<const v8f*>(p);
  v8s h;
#pragma unroll
  for (int j = 0; j < 8; ++j) h[j] = (short)f2bf(x[j]);
  return h;
}
__device__ __forceinline__ void gl16(const u16* g, u16* lds_base_uniform) {
  __builtin_amdgcn_global_load_lds(
      (const __attribute__((address_space(1))) u32*)g,
      (__attribute__((address_space(3))) u32*)lds_base_uniform, 16, 0, 0);
}

// ---------- merged pre-convert: q,k,v -> single bf16 planes ----------
__global__ __launch_bounds__(256) void cvt_qkv(
    const float* __restrict__ q, const float* __restrict__ k,
    const float* __restrict__ v, u16* __restrict__ qxb,
    u16* __restrict__ kxb, u16* __restrict__ vxb) {
  const unsigned total = 3u << 20;
  for (unsigned g = blockIdx.x * 256 + threadIdx.x; g < total;
       g += gridDim.x * 256) {
    unsigned r = g >> 20, local = g & ((1u << 20) - 1), i = local * 4;
    const float* src = (r == 0) ? q : (r == 1) ? k : v;
    u16* dst = (r == 0) ? qxb : (r == 1) ? kxb : vxb;
    float4 x = *reinterpret_cast<const float4*>(src + i);
    ushort4 h;
    h.x = f2bf(x.x); h.y = f2bf(x.y); h.z = f2bf(x.z); h.w = f2bf(x.w);
    *reinterpret_cast<ushort4*>(dst + i) = h;
  }
}
__global__ __launch_bounds__(256) void cvt_w4(
    const float* __restrict__ wq, const float* __restrict__ wk,
    const float* __restrict__ wv, const float* __restrict__ fw,
    u16* __restrict__ wqb, u16* __restrict__ wkb, u16* __restrict__ wvb,
    u16* __restrict__ fwb) {
  const unsigned total = 4u << 18;
  for (unsigned g = blockIdx.x * 256 + threadIdx.x; g < total;
       g += gridDim.x * 256) {
    unsigned r = g >> 18, local = g & ((1u << 18) - 1), i = local * 4;
    const float* src = (r == 0) ? wq : (r == 1) ? wk : (r == 2) ? wv : fw;
    u16* dst = (r == 0) ? wqb : (r == 1) ? wkb : (r == 2) ? wvb : fwb;
    float4 x = *reinterpret_cast<const float4*>(src + i);
    ushort4 h;
    h.x = f2bf(x.x); h.y = f2bf(x.y); h.z = f2bf(x.z); h.w = f2bf(x.w);
    *reinterpret_cast<ushort4*>(dst + i) = h;
  }
}

// ---------- projection GEMM with dead-row-tile zero-fill ----------
__global__ __launch_bounds__(256) void gemm_proj(
    const u16* __restrict__ qxb, const u16* __restrict__ kxb,
    const u16* __restrict__ vxb, const u16* __restrict__ wqb,
    const u16* __restrict__ wkb, const u16* __restrict__ wvb,
    const float* __restrict__ b_qs, const float* __restrict__ b_ks,
    const float* __restrict__ b_vs, const int* __restrict__ seq_len,
    u16* __restrict__ qh, u16* __restrict__ kh, u16* __restrict__ vt) {
  __shared__ u16 As[128 * 32];
  __shared__ u16 Bs[128 * 32];
  const int bid = blockIdx.x;
  const int sel = bid >> 8;                // 0=q,1=k,2=v
  const int tb = bid & 255;
  const int row0 = (tb >> 3) * 128;
  const int col0 = (tb & 7) * 128;
  const int bb = row0 >> 10, pos0 = row0 & (SL - 1);
  const bool dead = pos0 >= seq_len[bb];   // rows never numerically consumed

  const int tid = threadIdx.x;
  const int wid = tid >> 6, l = tid & 63, lo4 = l & 15, hi2 = l >> 4;
  const int wm = wid >> 1, wn = wid & 1;

  v4f acc[4][4];
#pragma unroll
  for (int i = 0; i < 4; ++i)
#pragma unroll
    for (int j = 0; j < 4; ++j) acc[i][j] = (v4f){0.f, 0.f, 0.f, 0.f};

  if (!dead) {
    const u16* Xb = (sel == 0) ? qxb : (sel == 1) ? kxb : vxb;
    const u16* Wb = (sel == 0) ? wqb : (sel == 1) ? wkb : wvb;
    const int r0s = tid >> 2, c0s = (tid & 3) * 8;
    const int r1s = (tid + 256) >> 2;
    const int ub0 = (wid * 64) * 8;
    const int ub1 = (256 + wid * 64) * 8;
    for (int ks = 0; ks < 32; ++ks) {
      const int k0 = ks * 32;
      gl16(Xb + (size_t)(row0 + r0s) * DM + k0 + c0s, As + ub0);
      gl16(Xb + (size_t)(row0 + r1s) * DM + k0 + c0s, As + ub1);
      gl16(Wb + (size_t)(col0 + r0s) * DM + k0 + c0s, Bs + ub0);
      gl16(Wb + (size_t)(col0 + r1s) * DM + k0 + c0s, Bs + ub1);
      __syncthreads();
      v8s af[4], bf[4];
#pragma unroll
      for (int mi = 0; mi < 4; ++mi)
        af[mi] = *(const v8s*)&As[(wm * 64 + mi * 16 + lo4) * 32 + hi2 * 8];
#pragma unroll
      for (int ni = 0; ni < 4; ++ni)
        bf[ni] = *(const v8s*)&Bs[(wn * 64 + ni * 16 + lo4) * 32 + hi2 * 8];
#pragma unroll
      for (int mi = 0; mi < 4; ++mi)
#pragma unroll
        for (int ni = 0; ni < 4; ++ni)
          acc[mi][ni] = mfma_bf16(af[mi], bf[ni], acc[mi][ni]);
      __syncthreads();
    }
  }

  const float* bias = (sel == 0) ? b_qs : (sel == 1) ? b_ks : b_vs;
#pragma unroll
  for (int mi = 0; mi < 4; ++mi)
#pragma unroll
    for (int ni = 0; ni < 4; ++ni)
#pragma unroll
      for (int r = 0; r < 4; ++r) {
        int row = row0 + wm * 64 + mi * 16 + hi2 * 4 + r;
        int col = col0 + wn * 64 + ni * 16 + lo4;
        u16 ob = dead ? (u16)0 : f2bf(acc[mi][ni][r] + bias[col]);
        int b_ = row >> 10, pos = row & (SL - 1);
        int h = col >> 6, d = col & (HD - 1);
        if (sel < 2) {
          u16* out = sel ? kh : qh;
          out[((size_t)(b_ * NH + h) * SL + pos) * HD + d] = ob;
        } else {
          vt[((size_t)(b_ * NH + h) * HD + d) * SL + pos] = ob;
        }
      }
}

// ---------- attention with mask-aware compute skip ----------
__global__ __launch_bounds__(256) void attn_kernel(
    const u16* __restrict__ qh, const u16* __restrict__ kh,
    const u16* __restrict__ vt, const int* __restrict__ seq_len,
    float* __restrict__ attn_out, float* __restrict__ ctx) {
  const int bh = blockIdx.x;
  const int qt = blockIdx.y;
  const int b_ = bh >> 4, h = bh & 15;
  const int seqb = seq_len[b_];
  const int tid = threadIdx.x;

  float* aout = attn_out + ((size_t)(h * NB + b_) * SL + qt * 16) * SL;

  if (qt * 16 >= seqb) {
    const float4 z = make_float4(0.f, 0.f, 0.f, 0.f);
#pragma unroll
    for (int i = 0; i < 16; ++i) {
      int idx = (tid + i * 256) * 4;
      int row = idx >> 10, key = idx & 1023;
      *reinterpret_cast<float4*>(&aout[(size_t)row * SL + key]) = z;
    }
    int r2 = tid >> 4, c2 = (tid & 15) * 4;
    *reinterpret_cast<float4*>(
        &ctx[((size_t)b_ * SL + qt * 16 + r2) * DM + h * HD + c2]) = z;
    return;
  }

  const int wv = tid >> 6, l = tid & 63;
  const int lo4 = l & 15, hi2 = l >> 4;

  __shared__ u16 p_lds[16][1032];
  __shared__ float red_m[4][16];
  __shared__ float red_s[4][16];

  const u16* qp = qh + ((size_t)bh * SL + qt * 16 + lo4) * HD + hi2 * 8;
  v8s aq0 = *(const v8s*)(qp);
  v8s aq1 = *(const v8s*)(qp + 32);

  const int kbase = wv * 256;
  const u16* Kb = kh + (size_t)bh * SL * HD;

  v4f s[16];
#pragma unroll
  for (int kt = 0; kt < 16; ++kt) {
    const bool kact = (kbase + kt * 16) < seqb;
    v4f acc = (v4f){0.f, 0.f, 0.f, 0.f};
    int key = kbase + kt * 16 + lo4;
    if (kact) {
      const u16* kp = Kb + key * HD + hi2 * 8;
      v8s bk0 = *(const v8s*)kp;
      v8s bk1 = *(const v8s*)(kp + 32);
      acc = mfma_bf16(aq0, bk0, acc);
      acc = mfma_bf16(aq1, bk1, acc);
    }
    bool km = key >= seqb;
#pragma unroll
    for (int r = 0; r < 4; ++r)
      s[kt][r] = km ? -INFINITY : acc[r] * 0.125f;
  }

  float m[4];
#pragma unroll
  for (int r = 0; r < 4; ++r) {
    float mm = s[0][r];
#pragma unroll
    for (int kt = 1; kt < 16; ++kt) mm = fmaxf(mm, s[kt][r]);
    for (int d2 = 1; d2 < 16; d2 <<= 1) mm = fmaxf(mm, __shfl_xor(mm, d2));
    m[r] = mm;
  }
  if (lo4 == 0) {
#pragma unroll
    for (int r = 0; r < 4; ++r) red_m[wv][hi2 * 4 + r] = m[r];
  }
  __syncthreads();
#pragma unroll
  for (int r = 0; r < 4; ++r) {
    float mm = red_m[0][hi2 * 4 + r];
    mm = fmaxf(mm, red_m[1][hi2 * 4 + r]);
    mm = fmaxf(mm, red_m[2][hi2 * 4 + r]);
    mm = fmaxf(mm, red_m[3][hi2 * 4 + r]);
    m[r] = mm;
  }
  float sm[4] = {0.f, 0.f, 0.f, 0.f};
#pragma unroll
  for (int kt = 0; kt < 16; ++kt) {
#pragma unroll
    for (int r = 0; r < 4; ++r) {
      float p = __expf(s[kt][r] - m[r]);
      s[kt][r] = p;
      sm[r] += p;
    }
  }
#pragma unroll
  for (int r = 0; r < 4; ++r)
    for (int d2 = 1; d2 < 16; d2 <<= 1) sm[r] += __shfl_xor(sm[r], d2);
  if (lo4 == 0) {
#pragma unroll
    for (int r = 0; r < 4; ++r) red_s[wv][hi2 * 4 + r] = sm[r];
  }
  __syncthreads();
  float inv[4];
#pragma unroll
  for (int r = 0; r < 4; ++r) {
    float t = red_s[0][hi2 * 4 + r] + red_s[1][hi2 * 4 + r] +
              red_s[2][hi2 * 4 + r] + red_s[3][hi2 * 4 + r];
    inv[r] = 1.f / t;
  }
#pragma unroll
  for (int r = 0; r < 4; ++r) {
    int row = hi2 * 4 + r;
    bool qm = (qt * 16 + row) >= seqb;
    float sc = qm ? 0.f : inv[r];
#pragma unroll
    for (int kt = 0; kt < 16; ++kt) {
      int key = kbase + kt * 16 + lo4;
      p_lds[row][key] = f2bf(s[kt][r] * sc);
    }
  }
  __syncthreads();
#pragma unroll
  for (int i = 0; i < 16; ++i) {
    int idx = (tid + i * 256) * 4;
    int row = idx >> 10, key = idx & 1023;
    ushort4 pv = *(const ushort4*)&p_lds[row][key];
    float4 o4 = make_float4(bf2f(pv.x), bf2f(pv.y), bf2f(pv.z), bf2f(pv.w));
    *reinterpret_cast<float4*>(&aout[(size_t)row * SL + key]) = o4;
  }
  v4f o = (v4f){0.f, 0.f, 0.f, 0.f};
  const u16* vbase = vt + (size_t)bh * HD * SL + (wv * 16 + lo4) * SL + hi2 * 8;
#pragma unroll 8
  for (int c = 0; c < 32; ++c) {
    if (c * 32 < seqb) {   // wave-uniform; dead key-chunks have P==0
      v8s pa = *(const v8s*)&p_lds[lo4][c * 32 + hi2 * 8];
      v8s vb = *(const v8s*)(vbase + c * 32);
      o = mfma_bf16(pa, vb, o);
    }
  }
#pragma unroll
  for (int r = 0; r < 4; ++r) {
    int row = qt * 16 + hi2 * 4 + r;
    ctx[((size_t)b_ * SL + row) * DM + h * HD + wv * 16 + lo4] = o[r];
  }
}

// ---------- fc GEMM with dead-row fast path ----------
__global__ __launch_bounds__(256) void gemm_fc(
    const float* __restrict__ ctx, const u16* __restrict__ fcwb,
    const float* __restrict__ fcb, const float* __restrict__ resid,
    const int* __restrict__ seq_len, float* __restrict__ fcout) {
  __shared__ u16 As[128 * 32];
  __shared__ u16 Bs[128 * 32];
  const int row0 = (blockIdx.x >> 3) * 128;
  const int col0 = (blockIdx.x & 7) * 128;
  const int bb = row0 >> 10, pos0 = row0 & (SL - 1);
  const bool dead = pos0 >= seq_len[bb];   // ctx rows are exactly 0
  const int tid = threadIdx.x;
  const int wid = tid >> 6, l = tid & 63, lo4 = l & 15, hi2 = l >> 4;
  const int wm = wid >> 1, wn = wid & 1;

  v4f acc[4][4];
#pragma unroll
  for (int i = 0; i < 4; ++i)
#pragma unroll
    for (int j = 0; j < 4; ++j) acc[i][j] = (v4f){0.f, 0.f, 0.f, 0.f};

  if (!dead) {
    const int r0s = tid >> 2, c0s = (tid & 3) * 8;
    const int r1s = (tid + 256) >> 2;
    const int ub0 = (wid * 64) * 8;
    const int ub1 = (256 + wid * 64) * 8;
    for (int ks = 0; ks < 32; ++ks) {
      const int k0 = ks * 32;
      gl16(fcwb + (size_t)(col0 + r0s) * DM + k0 + c0s, Bs + ub0);
      gl16(fcwb + (size_t)(col0 + r1s) * DM + k0 + c0s, Bs + ub1);
      *(v8s*)&As[tid * 8] = cvt8h(ctx + (size_t)(row0 + r0s) * DM + k0 + c0s);
      *(v8s*)&As[(tid + 256) * 8] =
          cvt8h(ctx + (size_t)(row0 + r1s) * DM + k0 + c0s);
      __syncthreads();
      v8s af[4], bf[4];
#pragma unroll
      for (int mi = 0; mi < 4; ++mi)
        af[mi] = *(const v8s*)&As[(wm * 64 + mi * 16 + lo4) * 32 + hi2 * 8];
#pragma unroll
      for (int ni = 0; ni < 4; ++ni)
        bf[ni] = *(const v8s*)&Bs[(wn * 64 + ni * 16 + lo4) * 32 + hi2 * 8];
#pragma unroll
      for (int mi = 0; mi < 4; ++mi)
#pragma unroll
        for (int ni = 0; ni < 4; ++ni)
          acc[mi][ni] = mfma_bf16(af[mi], bf[ni], acc[mi][ni]);
      __syncthreads();
    }
  }
#pragma unroll
  for (int mi = 0; mi < 4; ++mi)
#pragma unroll
    for (int ni = 0; ni < 4; ++ni)
#pragma unroll
      for (int r = 0; r < 4; ++r) {
        int row = row0 + wm * 64 + mi * 16 + hi2 * 4 + r;
        int col = col0 + wn * 64 + ni * 16 + lo4;
        fcout[(size_t)row * DM + col] =
            acc[mi][ni][r] + fcb[col] + resid[(size_t)row * DM + col];
      }
}

// ---------- row LayerNorm ----------
__global__ __launch_bounds__(256) void ln_rows(
    const float* __restrict__ x, const float* __restrict__ lng,
    const float* __restrict__ lnb, float* __restrict__ out) {
  const int row = blockIdx.x * 4 + (threadIdx.x >> 6);
  const int l = threadIdx.x & 63;
  const float* xr = x + (size_t)row * DM;
  float4 v[4];
  float s = 0.f, q2 = 0.f;
#pragma unroll
  for (int j = 0; j < 4; ++j) {
    v[j] = *reinterpret_cast<const float4*>(xr + l * 4 + j * 256);
    s += v[j].x + v[j].y + v[j].z + v[j].w;
    q2 += v[j].x * v[j].x + v[j].y * v[j].y + v[j].z * v[j].z + v[j].w * v[j].w;
  }
#pragma unroll
  for (int d = 1; d < 64; d <<= 1) {
    s += __shfl_xor(s, d);
    q2 += __shfl_xor(q2, d);
  }
  const float mean = s * (1.f / DM);
  const float var = q2 * (1.f / DM) - mean * mean;
  const float rstd = rsqrtf(var + 1e-5f);
#pragma unroll
  for (int j = 0; j < 4; ++j) {
    int c = l * 4 + j * 256;
    float4 g = *reinterpret_cast<const float4*>(lng + c);
    float4 b = *reinterpret_cast<const float4*>(lnb + c);
    float4 y;
    y.x = (v[j].x - mean) * rstd * g.x + b.x;
    y.y = (v[j].y - mean) * rstd * g.y + b.y;
    y.z = (v[j].z - mean) * rstd * g.z + b.z;
    y.w = (v[j].w - mean) * rstd * g.w + b.w;
    *reinterpret_cast<float4*>(out + (size_t)row * DM + c) = y;
  }
}

extern "C" void kernel_launch(void* const* d_in, const int* in_sizes, int n_in,
                              void* d_out, int out_size, void* d_ws, size_t ws_size,
                              hipStream_t stream) {
  const float* q = (const float*)d_in[0];
  const float* k = (const float*)d_in[1];
  const float* v = (const float*)d_in[2];
  const int* seq_len = (const int*)d_in[3];
  const float* w_qs = (const float*)d_in[4];
  const float* b_qs = (const float*)d_in[5];
  const float* w_ks = (const float*)d_in[6];
  const float* b_ks = (const float*)d_in[7];
  const float* w_vs = (const float*)d_in[8];
  const float* b_vs = (const float*)d_in[9];
  const float* fcw = (const float*)d_in[10];
  const float* fcb = (const float*)d_in[11];
  const float* lng = (const float*)d_in[12];
  const float* lnb = (const float*)d_in[13];

  float* out0 = (float*)d_out;
  float* attn_out = out0 + (size_t)NB * SL * DM;

  const size_t PLANE = (size_t)NB * SL * DM;
  const size_t WSZ = (size_t)DM * DM;
  u16* wsu = (u16*)d_ws;
  u16* qh = wsu;
  u16* kh = wsu + PLANE;
  u16* vt = wsu + 2 * PLANE;
  u16* fcwb = wsu + 3 * PLANE;
  float* ctx = out0;

  u16* satt = (u16*)attn_out;
  u16* qxb = satt;
  u16* kxb = satt + PLANE;
  u16* vxb = satt + 2 * PLANE;
  u16* wqb = satt + 3 * PLANE;
  u16* wkb = satt + 3 * PLANE + WSZ;
  u16* wvb = satt + 3 * PLANE + 2 * WSZ;

  float* fcout = (float*)d_ws;

  cvt_qkv<<<3072, 256, 0, stream>>>(q, k, v, qxb, kxb, vxb);
  cvt_w4<<<1024, 256, 0, stream>>>(w_qs, w_ks, w_vs, fcw, wqb, wkb, wvb, fcwb);
  gemm_proj<<<768, 256, 0, stream>>>(qxb, kxb, vxb, wqb, wkb, wvb,
                                     b_qs, b_ks, b_vs, seq_len, qh, kh, vt);
  attn_kernel<<<dim3(64, 64), 256, 0, stream>>>(qh, kh, vt, seq_len, attn_out, ctx);
  gemm_fc<<<256, 256, 0, stream>>>(ctx, fcwb, fcb, q, seq_len, fcout);
  ln_rows<<<1024, 256, 0, stream>>>(fcout, lng, lnb, out0);
}